// Round 14
// baseline (262.654 us; speedup 1.0000x reference)
//
#include <hip/hip_runtime.h>
#include <math.h>

#define NWIN 4096    // (64/4)^3 windows

typedef unsigned short u16;
typedef __bf16 bf16;
typedef __attribute__((ext_vector_type(8))) __bf16 bf16x8;
typedef __attribute__((ext_vector_type(4))) float f32x4;

__device__ __forceinline__ u16 f2b(float f){
  return __builtin_bit_cast(u16, (bf16)f);
}
__device__ __forceinline__ float wred_sum(float v){
  #pragma unroll
  for (int off = 32; off; off >>= 1) v += __shfl_xor(v, off);
  return v;
}
__device__ __forceinline__ float grp16_sum(float v){
  v += __shfl_xor(v, 1); v += __shfl_xor(v, 2);
  v += __shfl_xor(v, 4); v += __shfl_xor(v, 8);
  return v;
}
// GELU, sigmoid form: v*sigmoid(1.5957692*(v+0.044715 v^3)).
__device__ __forceinline__ float gelu(float v){
  float v2 = v * v;
  float inner = fmaf(v2, -0.07135806f, -1.5957692f);
  float e = __expf(v * inner);
  return v * __builtin_amdgcn_rcpf(1.0f + e);
}

// ---- LDS fragment helpers: bf16 tiles, XOR-swizzled (col ^ ((row&7)<<3)) ----
template<int STRIDE>
__device__ __forceinline__ bf16x8 ldfrag(const u16* m, int rowbase, int colbase, int lane){
  int row = rowbase + (lane & 15);
  int col = colbase + ((lane >> 4) << 3);
  return *(const bf16x8*)&m[row * STRIDE + (col ^ ((row & 7) << 3))];
}
template<int STRIDE>
__device__ __forceinline__ void stfrag(u16* m, int rowbase, int colbase, f32x4 v, float s, int lane){
  int col = colbase + (lane & 15);
  int r0  = rowbase + ((lane >> 4) << 2);
  #pragma unroll
  for (int r = 0; r < 4; ++r){
    int row = r0 + r;
    m[row * STRIDE + (col ^ ((row & 7) << 3))] = f2b(v[r] * s);
  }
}
// store transposed: element (row,col) -> m[col][row]
__device__ __forceinline__ void stfragT(u16* m, int rowbase, int colbase, f32x4 v, int lane){
  int col = colbase + (lane & 15);
  int r0  = rowbase + ((lane >> 4) << 2);
  #pragma unroll
  for (int r = 0; r < 4; ++r){
    int row = r0 + r;
    m[col * 64 + (row ^ ((col & 7) << 3))] = f2b(v[r]);
  }
}

// ---------------- prep: weights -> bf16 B-fragment order in d_ws ----------------
// wfq: [mat3][head4][kk2][ct4][lane64][8]   49152 u16  (mat2 = U_h = Wv_h @ Wo_h, FOLDED)
// (49152..65536 unused — old wfo slot, kept for layout stability)
// wf1: [kk2][nt16][lane64][8]               16384 u16 @ 65536
// wf2: [kk8][nt4][lane64][8]                16384 u16 @ 81920
// bias2: 64 fp32 @ u16-offset 98304         (bo + sum_h bv_h @ Wo_h)
__global__ __launch_bounds__(256) void k_prep(
    const float* __restrict__ wq, const float* __restrict__ wk,
    const float* __restrict__ wv, const float* __restrict__ wo,
    const float* __restrict__ w1, const float* __restrict__ w2,
    const float* __restrict__ bv, const float* __restrict__ bo,
    u16* __restrict__ wfq){
  int idx = blockIdx.x * 256 + threadIdx.x;
  if (idx >= 98368) return;
  int e = idx & 7, lane = (idx >> 3) & 63;
  if (idx < 49152){
    int ct = (idx >> 9) & 3, kk = (idx >> 11) & 1, hh = (idx >> 12) & 3, m = idx >> 14;
    int c = kk * 32 + ((lane >> 4) << 3) + e;
    int d = (ct << 4) + (lane & 15);
    if (m < 2){
      const float* W = (m == 0) ? wq : wk;
      wfq[idx] = f2b(W[(c * 4 + hh) * 64 + d]);
    } else {
      // U_h[c][d] = sum_k Wv[(c,hh),k] * Wo[(hh,k),d]
      float s = 0.f;
      for (int k = 0; k < 64; ++k)
        s += wv[(c * 4 + hh) * 64 + k] * wo[(hh * 64 + k) * 64 + d];
      wfq[idx] = f2b(s);
    }
  } else if (idx < 65536){
    // old wfo slot: unused after the fold
  } else if (idx < 81920){
    int j = idx - 65536;
    int nt = (j >> 9) & 15, kk = (j >> 13) & 1;
    int c = kk * 32 + ((lane >> 4) << 3) + e;
    int f = nt * 16 + (lane & 15);
    wfq[idx] = f2b(w1[c * 256 + f]);
  } else if (idx < 98304){
    int j = idx - 81920;
    int nt = (j >> 9) & 3, kk = (j >> 11) & 7;
    int f = kk * 32 + ((lane >> 4) << 3) + e;
    int c = nt * 16 + (lane & 15);
    wfq[idx] = f2b(w2[f * 64 + c]);
  } else {
    int c = idx - 98304;          // 0..63
    float s = bo[c];
    for (int k = 0; k < 256; ++k) // hh*64+d
      s += bv[k] * wo[k * 64 + c];
    ((float*)(wfq + 98304))[c] = s;
  }
}

// ------- fused LN1 + window MHA (out-proj folded, HEAD-PAIR double-buffered K/V') -------
//        + x2 + LN2 + FFN (all MFMA)
// Per head-pair: Phase A stores K,V' for BOTH heads (1 barrier), Phase B runs
// Q/QK^T/softmax/PV for both heads with no intervening barrier (Q/P wave-private).
// Barriers: 9 -> 5 per block. 48KB LDS (6 x [64][64] bf16).
__global__ __launch_bounds__(256, 4) void k_mega(
    const float* __restrict__ x,
    const float* __restrict__ ln1g, const float* __restrict__ ln1b,
    const float* __restrict__ bq, const float* __restrict__ bk,
    const float* __restrict__ ln2g, const float* __restrict__ ln2b,
    const float* __restrict__ b1, const float* __restrict__ b2,
    const u16* __restrict__ wf,
    float* __restrict__ out){
  __shared__ alignas(16) u16 sh[24576];   // 48KB
  u16* hs  = sh;            // LN1(x); later LN2 result; later y1 cb0 (per-wave rows)
  u16* qs  = sh + 4096;     // Q -> P (wave-private rows); later y1 cb1
  u16* ks0 = sh + 8192;     // K even head (cross-wave); later y1 cb2
  u16* ks1 = sh + 12288;    // K odd head (cross-wave);  later y1 cb3
  u16* vt0 = sh + 16384;    // V'^T even head (cross-wave)
  u16* vt1 = sh + 20480;    // V'^T odd head (cross-wave)
  const u16* wfq = wf;
  const u16* wf1 = wf + 65536;
  const u16* wf2 = wf + 81920;
  const float* bias2 = (const float*)(wf + 98304);

  int tid = threadIdx.x, wg = tid >> 6, lane = tid & 63;
  int win = blockIdx.x;
  int d0 = (win >> 8) << 2, h0 = ((win >> 4) & 15) << 2, w0 = (win & 15) << 2;
  int tb = wg * 16;
  int c0 = lane & 15, g4 = (lane >> 4) << 2;

  // ---- load own rows + LN1 -> hs (bf16, swizzled). Own rows: no barrier. ----
  {
    float gv = ln1g[lane], bb = ln1b[lane];
    #pragma unroll
    for (int j = 0; j < 16; ++j){
      int l = tb + j;
      int gd = d0 + (l >> 4), gh = h0 + ((l >> 2) & 3), gw = w0 + (l & 3);
      float v = x[((gd * 64 + gh) * 64 + gw) * 64 + lane];
      float mn = wred_sum(v) * 0.015625f;
      float dv = v - mn;
      float var = wred_sum(dv * dv) * 0.015625f;
      float n = dv * rsqrtf(var + 1e-5f) * gv + bb;
      hs[l * 64 + (lane ^ ((l & 7) << 3))] = f2b(n);
    }
  }

  f32x4 oacc[4];
  #pragma unroll
  for (int ct = 0; ct < 4; ++ct){
    float b0 = bias2[ct * 16 + c0];
    oacc[ct] = (f32x4){b0, b0, b0, b0};
  }

  #pragma unroll
  for (int hp = 0; hp < 2; ++hp){
    // ---- Phase A: K and V' for heads 2hp, 2hp+1 ----
    #pragma unroll
    for (int hi = 0; hi < 2; ++hi){
      int hh = hp * 2 + hi;
      u16* ksb = hi ? ks1 : ks0;
      u16* vtb = hi ? vt1 : vt0;
      {
        f32x4 acc[4];
        #pragma unroll
        for (int ct = 0; ct < 4; ++ct){
          float bb = bk[hh * 64 + ct * 16 + c0];
          acc[ct] = (f32x4){bb, bb, bb, bb};
        }
        #pragma unroll
        for (int kk = 0; kk < 2; ++kk){
          bf16x8 a = ldfrag<64>(hs, tb, kk * 32, lane);
          const u16* base = wfq + 16384 + ((hh * 2 + kk) * 4) * 512 + lane * 8;
          #pragma unroll
          for (int ct = 0; ct < 4; ++ct)
            acc[ct] = __builtin_amdgcn_mfma_f32_16x16x32_bf16(
                a, *(const bf16x8*)(base + ct * 512), acc[ct], 0, 0, 0);
        }
        #pragma unroll
        for (int ct = 0; ct < 4; ++ct) stfrag<64>(ksb, tb, ct * 16, acc[ct], 1.0f, lane);
      }
      {
        f32x4 acc[4];
        #pragma unroll
        for (int ct = 0; ct < 4; ++ct) acc[ct] = (f32x4){0.f, 0.f, 0.f, 0.f};
        #pragma unroll
        for (int kk = 0; kk < 2; ++kk){
          bf16x8 a = ldfrag<64>(hs, tb, kk * 32, lane);
          const u16* base = wfq + 32768 + ((hh * 2 + kk) * 4) * 512 + lane * 8;
          #pragma unroll
          for (int ct = 0; ct < 4; ++ct)
            acc[ct] = __builtin_amdgcn_mfma_f32_16x16x32_bf16(
                a, *(const bf16x8*)(base + ct * 512), acc[ct], 0, 0, 0);
        }
        #pragma unroll
        for (int ct = 0; ct < 4; ++ct) stfragT(vtb, tb, ct * 16, acc[ct], lane);  // V'^T
      }
    }
    __syncthreads();   // K/V' for both heads visible to all waves

    // ---- Phase B: both heads, no intervening barrier ----
    #pragma unroll
    for (int hi = 0; hi < 2; ++hi){
      int hh = hp * 2 + hi;
      const u16* ksb = hi ? ks1 : ks0;
      const u16* vtb = hi ? vt1 : vt0;

      // Q (wave-private rows of qs; folded 1/sqrt(64))
      {
        f32x4 acc[4];
        #pragma unroll
        for (int ct = 0; ct < 4; ++ct){
          float bb = bq[hh * 64 + ct * 16 + c0];
          acc[ct] = (f32x4){bb, bb, bb, bb};
        }
        #pragma unroll
        for (int kk = 0; kk < 2; ++kk){
          bf16x8 a = ldfrag<64>(hs, tb, kk * 32, lane);
          const u16* base = wfq + ((hh * 2 + kk) * 4) * 512 + lane * 8;
          #pragma unroll
          for (int ct = 0; ct < 4; ++ct)
            acc[ct] = __builtin_amdgcn_mfma_f32_16x16x32_bf16(
                a, *(const bf16x8*)(base + ct * 512), acc[ct], 0, 0, 0);
        }
        #pragma unroll
        for (int ct = 0; ct < 4; ++ct) stfrag<64>(qs, tb, ct * 16, acc[ct], 0.125f, lane);
      }

      // att = Q K^T (Q fully consumed before P overwrites qs)
      f32x4 att[4];
      #pragma unroll
      for (int ct = 0; ct < 4; ++ct) att[ct] = (f32x4){0.f, 0.f, 0.f, 0.f};
      #pragma unroll
      for (int kk = 0; kk < 2; ++kk){
        bf16x8 a = ldfrag<64>(qs, tb, kk * 32, lane);
        #pragma unroll
        for (int ct = 0; ct < 4; ++ct)
          att[ct] = __builtin_amdgcn_mfma_f32_16x16x32_bf16(
              a, ldfrag<64>(ksb, ct * 16, kk * 32, lane), att[ct], 0, 0, 0);
      }

      // in-register softmax over m
      #pragma unroll
      for (int r = 0; r < 4; ++r){
        float m0 = fmaxf(fmaxf(att[0][r], att[1][r]), fmaxf(att[2][r], att[3][r]));
        m0 = fmaxf(m0, __shfl_xor(m0, 1));
        m0 = fmaxf(m0, __shfl_xor(m0, 2));
        m0 = fmaxf(m0, __shfl_xor(m0, 4));
        m0 = fmaxf(m0, __shfl_xor(m0, 8));
        float e0 = __expf(att[0][r] - m0), e1 = __expf(att[1][r] - m0);
        float e2 = __expf(att[2][r] - m0), e3 = __expf(att[3][r] - m0);
        float s = grp16_sum(e0 + e1 + e2 + e3);
        float inv = 1.0f / s;
        att[0][r] = e0 * inv; att[1][r] = e1 * inv;
        att[2][r] = e2 * inv; att[3][r] = e3 * inv;
      }
      #pragma unroll
      for (int ct = 0; ct < 4; ++ct) stfrag<64>(qs, tb, ct * 16, att[ct], 1.0f, lane);  // P

      // oacc += P V'  (out-proj folded; fp32 accumulate, no LDS round-trip)
      #pragma unroll
      for (int kk = 0; kk < 2; ++kk){
        bf16x8 a = ldfrag<64>(qs, tb, kk * 32, lane);
        #pragma unroll
        for (int ct = 0; ct < 4; ++ct)
          oacc[ct] = __builtin_amdgcn_mfma_f32_16x16x32_bf16(
              a, ldfrag<64>(vtb, ct * 16, kk * 32, lane), oacc[ct], 0, 0, 0);
      }
    }
    __syncthreads();   // all reads of K/V' done before next pair overwrites (or FFN reuse)
  }

  // ======== fused x2 + LN2 + FFN (wave-private rows from here: no barriers) ========
  {
    float g2[4], b2l[4];
    #pragma unroll
    for (int ct = 0; ct < 4; ++ct){
      g2[ct] = ln2g[ct * 16 + c0];
      b2l[ct] = ln2b[ct * 16 + c0];
    }
    #pragma unroll
    for (int r = 0; r < 4; ++r){
      float v0 = 2.0f * oacc[0][r], v1 = 2.0f * oacc[1][r];
      float v2 = 2.0f * oacc[2][r], v3 = 2.0f * oacc[3][r];
      float s = grp16_sum(v0 + v1 + v2 + v3);
      float mn = s * 0.015625f;
      float d0f = v0 - mn, d1 = v1 - mn, d2 = v2 - mn, d3 = v3 - mn;
      float q = grp16_sum(d0f*d0f + d1*d1 + d2*d2 + d3*d3);
      float rs = rsqrtf(q * 0.015625f + 1e-5f);
      int row = tb + g4 + r;
      hs[row * 64 + ((0 * 16 + c0) ^ ((row & 7) << 3))] = f2b(d0f * rs * g2[0] + b2l[0]);
      hs[row * 64 + ((1 * 16 + c0) ^ ((row & 7) << 3))] = f2b(d1 * rs * g2[1] + b2l[1]);
      hs[row * 64 + ((2 * 16 + c0) ^ ((row & 7) << 3))] = f2b(d2 * rs * g2[2] + b2l[2]);
      hs[row * 64 + ((3 * 16 + c0) ^ ((row & 7) << 3))] = f2b(d3 * rs * g2[3] + b2l[3]);
    }
  }

  // ---- GEMM1: [16,64] x [64,256] -> y1 (GELU, bf16) ----
  // y1 col-block cb -> buffer cb (sh + cb*4096) at this wave's own rows tb..tb+15.
  {
    bf16x8 a0 = ldfrag<64>(hs, tb, 0, lane);
    bf16x8 a1 = ldfrag<64>(hs, tb, 32, lane);
    #pragma unroll
    for (int half = 0; half < 2; ++half){
      f32x4 acc1[8];
      #pragma unroll
      for (int nt = 0; nt < 8; ++nt){
        float bb = b1[(half * 8 + nt) * 16 + c0];
        acc1[nt] = (f32x4){bb, bb, bb, bb};
      }
      const u16* base0 = wf1 + half * 8 * 512 + lane * 8;
      #pragma unroll
      for (int nt = 0; nt < 8; ++nt)
        acc1[nt] = __builtin_amdgcn_mfma_f32_16x16x32_bf16(
            a0, *(const bf16x8*)(base0 + nt * 512), acc1[nt], 0, 0, 0);
      #pragma unroll
      for (int nt = 0; nt < 8; ++nt)
        acc1[nt] = __builtin_amdgcn_mfma_f32_16x16x32_bf16(
            a1, *(const bf16x8*)(base0 + 16 * 512 + nt * 512), acc1[nt], 0, 0, 0);
      #pragma unroll
      for (int nt = 0; nt < 8; ++nt){
        f32x4 v = acc1[nt];
        f32x4 y;
        #pragma unroll
        for (int r = 0; r < 4; ++r) y[r] = gelu(v[r]);
        int gnt = half * 8 + nt;                 // global col tile 0..15
        stfrag<64>(sh + (gnt >> 2) * 4096, tb, (gnt & 3) * 16, y, 1.0f, lane);
      }
    }
  }

  // ---- GEMM2: [16,256] x [256,64] -> out (fp32, merged voxel layout) ----
  {
    f32x4 acc2[4];
    #pragma unroll
    for (int nt = 0; nt < 4; ++nt){
      float bb = b2[nt * 16 + c0];
      acc2[nt] = (f32x4){bb, bb, bb, bb};
    }
    #pragma unroll
    for (int kk = 0; kk < 8; ++kk){
      bf16x8 a = ldfrag<64>(sh + (kk >> 1) * 4096, tb, (kk & 1) * 32, lane);
      const u16* base = wf2 + kk * 4 * 512 + lane * 8;
      #pragma unroll
      for (int nt = 0; nt < 4; ++nt)
        acc2[nt] = __builtin_amdgcn_mfma_f32_16x16x32_bf16(
            a, *(const bf16x8*)(base + nt * 512), acc2[nt], 0, 0, 0);
    }
    #pragma unroll
    for (int r = 0; r < 4; ++r){
      int l = tb + g4 + r;
      int gd = d0 + (l >> 4), gh = h0 + ((l >> 2) & 3), gw = w0 + (l & 3);
      float* orow = out + ((gd * 64 + gh) * 64 + gw) * 64;
      #pragma unroll
      for (int nt = 0; nt < 4; ++nt)
        orow[nt * 16 + c0] = acc2[nt][r];
    }
  }
}

extern "C" void kernel_launch(void* const* d_in, const int* in_sizes, int n_in,
                              void* d_out, int out_size, void* d_ws, size_t ws_size,
                              hipStream_t stream){
  const float* x    = (const float*)d_in[0];
  const float* ln1g = (const float*)d_in[1];
  const float* ln1b = (const float*)d_in[2];
  const float* wq   = (const float*)d_in[3];
  const float* bq   = (const float*)d_in[4];
  const float* wk   = (const float*)d_in[5];
  const float* bk   = (const float*)d_in[6];
  const float* wv   = (const float*)d_in[7];
  const float* bv   = (const float*)d_in[8];
  const float* wo   = (const float*)d_in[9];
  const float* bo   = (const float*)d_in[10];
  const float* ln2g = (const float*)d_in[11];
  const float* ln2b = (const float*)d_in[12];
  const float* w1   = (const float*)d_in[13];
  const float* b1   = (const float*)d_in[14];
  const float* w2   = (const float*)d_in[15];
  const float* b2   = (const float*)d_in[16];

  u16* wf = (u16*)d_ws;     // 192KB bf16 weight fragments + 256B fp32 bias2
  float* out = (float*)d_out;

  k_prep<<<385, 256, 0, stream>>>(wq, wk, wv, wo, w1, w2, bv, bo, wf);
  k_mega<<<NWIN, 256, 0, stream>>>(x, ln1g, ln1b, bq, bk,
                                   ln2g, ln2b, b1, b2, wf, out);
}

// Round 15
// 167.258 us; speedup vs baseline: 1.5704x; 1.5704x over previous
//
#include <hip/hip_runtime.h>
#include <math.h>

#define NWIN 4096    // (64/4)^3 windows

typedef unsigned short u16;
typedef __bf16 bf16;
typedef __attribute__((ext_vector_type(8))) __bf16 bf16x8;
typedef __attribute__((ext_vector_type(4))) float f32x4;

__device__ __forceinline__ u16 f2b(float f){
  return __builtin_bit_cast(u16, (bf16)f);
}
__device__ __forceinline__ float wred_sum(float v){
  #pragma unroll
  for (int off = 32; off; off >>= 1) v += __shfl_xor(v, off);
  return v;
}
__device__ __forceinline__ float grp16_sum(float v){
  v += __shfl_xor(v, 1); v += __shfl_xor(v, 2);
  v += __shfl_xor(v, 4); v += __shfl_xor(v, 8);
  return v;
}
// GELU, sigmoid form: v*sigmoid(1.5957692*(v+0.044715 v^3)).
__device__ __forceinline__ float gelu(float v){
  float v2 = v * v;
  float inner = fmaf(v2, -0.07135806f, -1.5957692f);
  float e = __expf(v * inner);
  return v * __builtin_amdgcn_rcpf(1.0f + e);
}

// ---- LDS fragment helpers: bf16 tiles, XOR-swizzled (col ^ ((row&7)<<3)) ----
template<int STRIDE>
__device__ __forceinline__ bf16x8 ldfrag(const u16* m, int rowbase, int colbase, int lane){
  int row = rowbase + (lane & 15);
  int col = colbase + ((lane >> 4) << 3);
  return *(const bf16x8*)&m[row * STRIDE + (col ^ ((row & 7) << 3))];
}
template<int STRIDE>
__device__ __forceinline__ void stfrag(u16* m, int rowbase, int colbase, f32x4 v, float s, int lane){
  int col = colbase + (lane & 15);
  int r0  = rowbase + ((lane >> 4) << 2);
  #pragma unroll
  for (int r = 0; r < 4; ++r){
    int row = r0 + r;
    m[row * STRIDE + (col ^ ((row & 7) << 3))] = f2b(v[r] * s);
  }
}
// store transposed: element (row,col) -> m[col][row]
__device__ __forceinline__ void stfragT(u16* m, int rowbase, int colbase, f32x4 v, int lane){
  int col = colbase + (lane & 15);
  int r0  = rowbase + ((lane >> 4) << 2);
  #pragma unroll
  for (int r = 0; r < 4; ++r){
    int row = r0 + r;
    m[col * 64 + (row ^ ((col & 7) << 3))] = f2b(v[r]);
  }
}

// ---------------- prep: weights -> bf16 B-fragment order in d_ws ----------------
// wfq: [mat3][head4][kk2][ct4][lane64][8]   49152 u16  (mat2 = U_h = Wv_h @ Wo_h, FOLDED)
// (49152..65536 unused — old wfo slot, kept for layout stability)
// wf1: [kk2][nt16][lane64][8]               16384 u16 @ 65536
// wf2: [kk8][nt4][lane64][8]                16384 u16 @ 81920
// bias2: 64 fp32 @ u16-offset 98304         (bo + sum_h bv_h @ Wo_h)
__global__ __launch_bounds__(256) void k_prep(
    const float* __restrict__ wq, const float* __restrict__ wk,
    const float* __restrict__ wv, const float* __restrict__ wo,
    const float* __restrict__ w1, const float* __restrict__ w2,
    const float* __restrict__ bv, const float* __restrict__ bo,
    u16* __restrict__ wfq){
  int idx = blockIdx.x * 256 + threadIdx.x;
  if (idx >= 98368) return;
  int e = idx & 7, lane = (idx >> 3) & 63;
  if (idx < 49152){
    int ct = (idx >> 9) & 3, kk = (idx >> 11) & 1, hh = (idx >> 12) & 3, m = idx >> 14;
    int c = kk * 32 + ((lane >> 4) << 3) + e;
    int d = (ct << 4) + (lane & 15);
    if (m < 2){
      const float* W = (m == 0) ? wq : wk;
      wfq[idx] = f2b(W[(c * 4 + hh) * 64 + d]);
    } else {
      // U_h[c][d] = sum_k Wv[(c,hh),k] * Wo[(hh,k),d]
      float s = 0.f;
      for (int k = 0; k < 64; ++k)
        s += wv[(c * 4 + hh) * 64 + k] * wo[(hh * 64 + k) * 64 + d];
      wfq[idx] = f2b(s);
    }
  } else if (idx < 65536){
    // old wfo slot: unused after the fold
  } else if (idx < 81920){
    int j = idx - 65536;
    int nt = (j >> 9) & 15, kk = (j >> 13) & 1;
    int c = kk * 32 + ((lane >> 4) << 3) + e;
    int f = nt * 16 + (lane & 15);
    wfq[idx] = f2b(w1[c * 256 + f]);
  } else if (idx < 98304){
    int j = idx - 81920;
    int nt = (j >> 9) & 3, kk = (j >> 11) & 7;
    int f = kk * 32 + ((lane >> 4) << 3) + e;
    int c = nt * 16 + (lane & 15);
    wfq[idx] = f2b(w2[f * 64 + c]);
  } else {
    int c = idx - 98304;          // 0..63
    float s = bo[c];
    for (int k = 0; k < 256; ++k) // hh*64+d
      s += bv[k] * wo[k * 64 + c];
    ((float*)(wfq + 98304))[c] = s;
  }
}

// ------- fused LN1 + window MHA (out-proj FOLDED into V) + x2 + LN2 + FFN -------
// ROUND 13 CHAMPION (reverted): V' = h @ (Wv_h Wo_h); PV accumulates directly
// into oacc (init = bias2). One block (4 waves) per window; wave owns 16 token
// rows. 32KB LDS, 2 barriers/head. 179us profiled / 167.6us bench, absmax 8.2e-4.
__global__ __launch_bounds__(256, 4) void k_mega(
    const float* __restrict__ x,
    const float* __restrict__ ln1g, const float* __restrict__ ln1b,
    const float* __restrict__ bq, const float* __restrict__ bk,
    const float* __restrict__ ln2g, const float* __restrict__ ln2b,
    const float* __restrict__ b1, const float* __restrict__ b2,
    const u16* __restrict__ wf,
    float* __restrict__ out){
  __shared__ alignas(16) u16 sh[16384];   // 32KB: 4 x [64][64] bf16 buffers
  u16* hs = sh;           // LN1(x); later LN2 result; later y1 col-block 0 (per-wave rows)
  u16* qs = sh + 4096;    // Q -> P (wave-private rows); later y1 cb1
  u16* ks = sh + 8192;    // K (cross-wave); later y1 cb2
  u16* vt = sh + 12288;   // V'^T (cross-wave); later y1 cb3
  const u16* wfq = wf;
  const u16* wf1 = wf + 65536;
  const u16* wf2 = wf + 81920;
  const float* bias2 = (const float*)(wf + 98304);

  int tid = threadIdx.x, wg = tid >> 6, lane = tid & 63;
  int win = blockIdx.x;
  int d0 = (win >> 8) << 2, h0 = ((win >> 4) & 15) << 2, w0 = (win & 15) << 2;
  int tb = wg * 16;
  int c0 = lane & 15, g4 = (lane >> 4) << 2;

  // ---- load own rows + LN1 -> hs (bf16, swizzled). Own rows: no barrier. ----
  {
    float gv = ln1g[lane], bb = ln1b[lane];
    #pragma unroll
    for (int j = 0; j < 16; ++j){
      int l = tb + j;
      int gd = d0 + (l >> 4), gh = h0 + ((l >> 2) & 3), gw = w0 + (l & 3);
      float v = x[((gd * 64 + gh) * 64 + gw) * 64 + lane];
      float mn = wred_sum(v) * 0.015625f;
      float dv = v - mn;
      float var = wred_sum(dv * dv) * 0.015625f;
      float n = dv * rsqrtf(var + 1e-5f) * gv + bb;
      hs[l * 64 + (lane ^ ((l & 7) << 3))] = f2b(n);
    }
  }

  f32x4 oacc[4];
  #pragma unroll
  for (int ct = 0; ct < 4; ++ct){
    float b0 = bias2[ct * 16 + c0];
    oacc[ct] = (f32x4){b0, b0, b0, b0};
  }

  for (int hh = 0; hh < 4; ++hh){
    // ---- Q/K/V' projection: three sequential passes (low reg pressure) ----
    #pragma unroll
    for (int m = 0; m < 3; ++m){
      f32x4 acc[4];
      #pragma unroll
      for (int ct = 0; ct < 4; ++ct){
        float bb = (m == 0) ? bq[hh * 64 + ct * 16 + c0]
                 : (m == 1) ? bk[hh * 64 + ct * 16 + c0] : 0.f;
        acc[ct] = (f32x4){bb, bb, bb, bb};
      }
      #pragma unroll
      for (int kk = 0; kk < 2; ++kk){
        bf16x8 a = ldfrag<64>(hs, tb, kk * 32, lane);
        const u16* base = wfq + m * 16384 + ((hh * 2 + kk) * 4) * 512 + lane * 8;
        #pragma unroll
        for (int ct = 0; ct < 4; ++ct)
          acc[ct] = __builtin_amdgcn_mfma_f32_16x16x32_bf16(
              a, *(const bf16x8*)(base + ct * 512), acc[ct], 0, 0, 0);
      }
      if (m == 0){
        #pragma unroll
        for (int ct = 0; ct < 4; ++ct) stfrag<64>(qs, tb, ct * 16, acc[ct], 0.125f, lane);
      } else if (m == 1){
        #pragma unroll
        for (int ct = 0; ct < 4; ++ct) stfrag<64>(ks, tb, ct * 16, acc[ct], 1.0f, lane);
      } else {
        #pragma unroll
        for (int ct = 0; ct < 4; ++ct) stfragT(vt, tb, ct * 16, acc[ct], lane);  // V'^T [c][m]
      }
    }
    __syncthreads();   // ks/vt read cross-wave

    // ---- att = Q K^T  (Q fully consumed from qs before P overwrites it) ----
    f32x4 att[4];
    #pragma unroll
    for (int ct = 0; ct < 4; ++ct) att[ct] = (f32x4){0.f, 0.f, 0.f, 0.f};
    #pragma unroll
    for (int kk = 0; kk < 2; ++kk){
      bf16x8 a = ldfrag<64>(qs, tb, kk * 32, lane);
      #pragma unroll
      for (int ct = 0; ct < 4; ++ct)
        att[ct] = __builtin_amdgcn_mfma_f32_16x16x32_bf16(
            a, ldfrag<64>(ks, ct * 16, kk * 32, lane), att[ct], 0, 0, 0);
    }

    // ---- in-register softmax over m ----
    #pragma unroll
    for (int r = 0; r < 4; ++r){
      float m0 = fmaxf(fmaxf(att[0][r], att[1][r]), fmaxf(att[2][r], att[3][r]));
      m0 = fmaxf(m0, __shfl_xor(m0, 1));
      m0 = fmaxf(m0, __shfl_xor(m0, 2));
      m0 = fmaxf(m0, __shfl_xor(m0, 4));
      m0 = fmaxf(m0, __shfl_xor(m0, 8));
      float e0 = __expf(att[0][r] - m0), e1 = __expf(att[1][r] - m0);
      float e2 = __expf(att[2][r] - m0), e3 = __expf(att[3][r] - m0);
      float s = grp16_sum(e0 + e1 + e2 + e3);
      float inv = 1.0f / s;
      att[0][r] = e0 * inv; att[1][r] = e1 * inv;
      att[2][r] = e2 * inv; att[3][r] = e3 * inv;
    }
    #pragma unroll
    for (int ct = 0; ct < 4; ++ct) stfrag<64>(qs, tb, ct * 16, att[ct], 1.0f, lane);  // P -> qs

    // ---- oacc += P V'  (out-proj folded into V'; fp32 accumulate, no LDS round-trip) ----
    #pragma unroll
    for (int kk = 0; kk < 2; ++kk){
      bf16x8 a = ldfrag<64>(qs, tb, kk * 32, lane);
      #pragma unroll
      for (int ct = 0; ct < 4; ++ct)
        oacc[ct] = __builtin_amdgcn_mfma_f32_16x16x32_bf16(
            a, ldfrag<64>(vt, ct * 16, kk * 32, lane), oacc[ct], 0, 0, 0);
    }
    __syncthreads();   // before next head overwrites ks/vt (and before FFN LDS reuse)
  }

  // ======== fused x2 + LN2 + FFN (wave-private rows from here: no barriers) ========
  {
    float g2[4], b2l[4];
    #pragma unroll
    for (int ct = 0; ct < 4; ++ct){
      g2[ct] = ln2g[ct * 16 + c0];
      b2l[ct] = ln2b[ct * 16 + c0];
    }
    #pragma unroll
    for (int r = 0; r < 4; ++r){
      float v0 = 2.0f * oacc[0][r], v1 = 2.0f * oacc[1][r];
      float v2 = 2.0f * oacc[2][r], v3 = 2.0f * oacc[3][r];
      float s = grp16_sum(v0 + v1 + v2 + v3);
      float mn = s * 0.015625f;
      float d0f = v0 - mn, d1 = v1 - mn, d2 = v2 - mn, d3 = v3 - mn;
      float q = grp16_sum(d0f*d0f + d1*d1 + d2*d2 + d3*d3);
      float rs = rsqrtf(q * 0.015625f + 1e-5f);
      int row = tb + g4 + r;
      hs[row * 64 + ((0 * 16 + c0) ^ ((row & 7) << 3))] = f2b(d0f * rs * g2[0] + b2l[0]);
      hs[row * 64 + ((1 * 16 + c0) ^ ((row & 7) << 3))] = f2b(d1 * rs * g2[1] + b2l[1]);
      hs[row * 64 + ((2 * 16 + c0) ^ ((row & 7) << 3))] = f2b(d2 * rs * g2[2] + b2l[2]);
      hs[row * 64 + ((3 * 16 + c0) ^ ((row & 7) << 3))] = f2b(d3 * rs * g2[3] + b2l[3]);
    }
  }

  // ---- GEMM1: [16,64] x [64,256] -> y1 (GELU, bf16) ----
  // y1 col-block cb (64 cols) lives in buffer cb at this wave's own rows tb..tb+15.
  // Preload both hs A-fragments BEFORE y1 overwrites the hs slice.
  {
    bf16x8 a0 = ldfrag<64>(hs, tb, 0, lane);
    bf16x8 a1 = ldfrag<64>(hs, tb, 32, lane);
    #pragma unroll
    for (int half = 0; half < 2; ++half){
      f32x4 acc1[8];
      #pragma unroll
      for (int nt = 0; nt < 8; ++nt){
        float bb = b1[(half * 8 + nt) * 16 + c0];
        acc1[nt] = (f32x4){bb, bb, bb, bb};
      }
      const u16* base0 = wf1 + half * 8 * 512 + lane * 8;
      #pragma unroll
      for (int nt = 0; nt < 8; ++nt)
        acc1[nt] = __builtin_amdgcn_mfma_f32_16x16x32_bf16(
            a0, *(const bf16x8*)(base0 + nt * 512), acc1[nt], 0, 0, 0);
      #pragma unroll
      for (int nt = 0; nt < 8; ++nt)
        acc1[nt] = __builtin_amdgcn_mfma_f32_16x16x32_bf16(
            a1, *(const bf16x8*)(base0 + 16 * 512 + nt * 512), acc1[nt], 0, 0, 0);
      #pragma unroll
      for (int nt = 0; nt < 8; ++nt){
        f32x4 v = acc1[nt];
        f32x4 y;
        #pragma unroll
        for (int r = 0; r < 4; ++r) y[r] = gelu(v[r]);
        int gnt = half * 8 + nt;                 // global col tile 0..15
        stfrag<64>(sh + (gnt >> 2) * 4096, tb, (gnt & 3) * 16, y, 1.0f, lane);
      }
    }
  }

  // ---- GEMM2: [16,256] x [256,64] -> out (fp32, merged voxel layout) ----
  {
    f32x4 acc2[4];
    #pragma unroll
    for (int nt = 0; nt < 4; ++nt){
      float bb = b2[nt * 16 + c0];
      acc2[nt] = (f32x4){bb, bb, bb, bb};
    }
    #pragma unroll
    for (int kk = 0; kk < 8; ++kk){
      bf16x8 a = ldfrag<64>(sh + (kk >> 1) * 4096, tb, (kk & 1) * 32, lane);
      const u16* base = wf2 + kk * 4 * 512 + lane * 8;
      #pragma unroll
      for (int nt = 0; nt < 4; ++nt)
        acc2[nt] = __builtin_amdgcn_mfma_f32_16x16x32_bf16(
            a, *(const bf16x8*)(base + nt * 512), acc2[nt], 0, 0, 0);
    }
    #pragma unroll
    for (int r = 0; r < 4; ++r){
      int l = tb + g4 + r;
      int gd = d0 + (l >> 4), gh = h0 + ((l >> 2) & 3), gw = w0 + (l & 3);
      float* orow = out + ((gd * 64 + gh) * 64 + gw) * 64;
      #pragma unroll
      for (int nt = 0; nt < 4; ++nt)
        orow[nt * 16 + c0] = acc2[nt][r];
    }
  }
}

extern "C" void kernel_launch(void* const* d_in, const int* in_sizes, int n_in,
                              void* d_out, int out_size, void* d_ws, size_t ws_size,
                              hipStream_t stream){
  const float* x    = (const float*)d_in[0];
  const float* ln1g = (const float*)d_in[1];
  const float* ln1b = (const float*)d_in[2];
  const float* wq   = (const float*)d_in[3];
  const float* bq   = (const float*)d_in[4];
  const float* wk   = (const float*)d_in[5];
  const float* bk   = (const float*)d_in[6];
  const float* wv   = (const float*)d_in[7];
  const float* bv   = (const float*)d_in[8];
  const float* wo   = (const float*)d_in[9];
  const float* bo   = (const float*)d_in[10];
  const float* ln2g = (const float*)d_in[11];
  const float* ln2b = (const float*)d_in[12];
  const float* w1   = (const float*)d_in[13];
  const float* b1   = (const float*)d_in[14];
  const float* w2   = (const float*)d_in[15];
  const float* b2   = (const float*)d_in[16];

  u16* wf = (u16*)d_ws;     // 192KB bf16 weight fragments + 256B fp32 bias2
  float* out = (float*)d_out;

  k_prep<<<385, 256, 0, stream>>>(wq, wk, wv, wo, w1, w2, bv, bo, wf);
  k_mega<<<NWIN, 256, 0, stream>>>(x, ln1g, ln1b, bq, bk,
                                   ln2g, ln2b, b1, b2, wf, out);
}

// Round 16
// 154.445 us; speedup vs baseline: 1.7006x; 1.0830x over previous
//
#include <hip/hip_runtime.h>
#include <math.h>

#define NWIN 4096    // (64/4)^3 windows

typedef unsigned short u16;
typedef __bf16 bf16;
typedef __attribute__((ext_vector_type(8))) __bf16 bf16x8;
typedef __attribute__((ext_vector_type(4))) float f32x4;

__device__ __forceinline__ u16 f2b(float f){
  return __builtin_bit_cast(u16, (bf16)f);
}

// ---- DPP cross-lane (VALU-pipe, ~2cyc vs ds_swizzle ~30cyc) ----
// quad_perm xor1 = [1,0,3,2] = 0xB1; xor2 = [2,3,0,1] = 0x4E;
// row_ror:4 = 0x124, row_ror:8 = 0x128 (any full-mixing perm works once quads uniform)
template<int CTRL>
__device__ __forceinline__ float dppf(float v){
  return __builtin_bit_cast(float, __builtin_amdgcn_update_dpp(
      0, __builtin_bit_cast(int, v), CTRL, 0xF, 0xF, false));
}
__device__ __forceinline__ float grp16_sum(float v){
  v += dppf<0xB1>(v);
  v += dppf<0x4E>(v);
  v += dppf<0x124>(v);
  v += dppf<0x128>(v);
  return v;
}
__device__ __forceinline__ float grp16_max(float v){
  v = fmaxf(v, dppf<0xB1>(v));
  v = fmaxf(v, dppf<0x4E>(v));
  v = fmaxf(v, dppf<0x124>(v));
  v = fmaxf(v, dppf<0x128>(v));
  return v;
}
__device__ __forceinline__ float wred_sum(float v){
  v = grp16_sum(v);           // 16-lane groups via DPP
  v += __shfl_xor(v, 16);     // cross-row (LDS pipe, 2 ops instead of 6)
  v += __shfl_xor(v, 32);
  return v;
}
// GELU, sigmoid form: v*sigmoid(1.5957692*(v+0.044715 v^3)).
__device__ __forceinline__ float gelu(float v){
  float v2 = v * v;
  float inner = fmaf(v2, -0.07135806f, -1.5957692f);
  float e = __expf(v * inner);
  return v * __builtin_amdgcn_rcpf(1.0f + e);
}

// ---- LDS fragment helpers: bf16 tiles, XOR-swizzled (col ^ ((row&7)<<3)) ----
template<int STRIDE>
__device__ __forceinline__ bf16x8 ldfrag(const u16* m, int rowbase, int colbase, int lane){
  int row = rowbase + (lane & 15);
  int col = colbase + ((lane >> 4) << 3);
  return *(const bf16x8*)&m[row * STRIDE + (col ^ ((row & 7) << 3))];
}
template<int STRIDE>
__device__ __forceinline__ void stfrag(u16* m, int rowbase, int colbase, f32x4 v, float s, int lane){
  int col = colbase + (lane & 15);
  int r0  = rowbase + ((lane >> 4) << 2);
  #pragma unroll
  for (int r = 0; r < 4; ++r){
    int row = r0 + r;
    m[row * STRIDE + (col ^ ((row & 7) << 3))] = f2b(v[r] * s);
  }
}
// store transposed: element (row,col) -> m[col][row]
__device__ __forceinline__ void stfragT(u16* m, int rowbase, int colbase, f32x4 v, int lane){
  int col = colbase + (lane & 15);
  int r0  = rowbase + ((lane >> 4) << 2);
  #pragma unroll
  for (int r = 0; r < 4; ++r){
    int row = r0 + r;
    m[col * 64 + (row ^ ((col & 7) << 3))] = f2b(v[r]);
  }
}

// ---------------- prep: weights -> bf16 B-fragment order in d_ws ----------------
// wfq: [mat3][head4][kk2][ct4][lane64][8]   49152 u16  (mat2 = U_h = Wv_h @ Wo_h, FOLDED)
// (49152..65536 unused — old wfo slot, kept for layout stability)
// wf1: [kk2][nt16][lane64][8]               16384 u16 @ 65536
// wf2: [kk8][nt4][lane64][8]                16384 u16 @ 81920
// bias2: 64 fp32 @ u16-offset 98304         (bo + sum_h bv_h @ Wo_h)
__global__ __launch_bounds__(256) void k_prep(
    const float* __restrict__ wq, const float* __restrict__ wk,
    const float* __restrict__ wv, const float* __restrict__ wo,
    const float* __restrict__ w1, const float* __restrict__ w2,
    const float* __restrict__ bv, const float* __restrict__ bo,
    u16* __restrict__ wfq){
  int idx = blockIdx.x * 256 + threadIdx.x;
  if (idx >= 98368) return;
  int e = idx & 7, lane = (idx >> 3) & 63;
  if (idx < 49152){
    int ct = (idx >> 9) & 3, kk = (idx >> 11) & 1, hh = (idx >> 12) & 3, m = idx >> 14;
    int c = kk * 32 + ((lane >> 4) << 3) + e;
    int d = (ct << 4) + (lane & 15);
    if (m < 2){
      const float* W = (m == 0) ? wq : wk;
      wfq[idx] = f2b(W[(c * 4 + hh) * 64 + d]);
    } else {
      // U_h[c][d] = sum_k Wv[(c,hh),k] * Wo[(hh,k),d]
      float s = 0.f;
      for (int k = 0; k < 64; ++k)
        s += wv[(c * 4 + hh) * 64 + k] * wo[(hh * 64 + k) * 64 + d];
      wfq[idx] = f2b(s);
    }
  } else if (idx < 65536){
    // old wfo slot: unused after the fold
  } else if (idx < 81920){
    int j = idx - 65536;
    int nt = (j >> 9) & 15, kk = (j >> 13) & 1;
    int c = kk * 32 + ((lane >> 4) << 3) + e;
    int f = nt * 16 + (lane & 15);
    wfq[idx] = f2b(w1[c * 256 + f]);
  } else if (idx < 98304){
    int j = idx - 81920;
    int nt = (j >> 9) & 3, kk = (j >> 11) & 7;
    int f = kk * 32 + ((lane >> 4) << 3) + e;
    int c = nt * 16 + (lane & 15);
    wfq[idx] = f2b(w2[f * 64 + c]);
  } else {
    int c = idx - 98304;          // 0..63
    float s = bo[c];
    for (int k = 0; k < 256; ++k) // hh*64+d
      s += bv[k] * wo[k * 64 + c];
    ((float*)(wfq + 98304))[c] = s;
  }
}

// ------- fused LN1 + window MHA (out-proj FOLDED into V) + x2 + LN2 + FFN -------
// ROUND 13 CHAMPION + DPP reductions (quad_perm/row_ror replace ds_swizzle shuffles
// in LN1/softmax/LN2 — same arithmetic, VALU-pipe instead of LDS-pipe).
// One block (4 waves) per window; wave owns 16 token rows. 32KB LDS.
__global__ __launch_bounds__(256, 4) void k_mega(
    const float* __restrict__ x,
    const float* __restrict__ ln1g, const float* __restrict__ ln1b,
    const float* __restrict__ bq, const float* __restrict__ bk,
    const float* __restrict__ ln2g, const float* __restrict__ ln2b,
    const float* __restrict__ b1, const float* __restrict__ b2,
    const u16* __restrict__ wf,
    float* __restrict__ out){
  __shared__ alignas(16) u16 sh[16384];   // 32KB: 4 x [64][64] bf16 buffers
  u16* hs = sh;           // LN1(x); later LN2 result; later y1 col-block 0 (per-wave rows)
  u16* qs = sh + 4096;    // Q -> P (wave-private rows); later y1 cb1
  u16* ks = sh + 8192;    // K (cross-wave); later y1 cb2
  u16* vt = sh + 12288;   // V'^T (cross-wave); later y1 cb3
  const u16* wfq = wf;
  const u16* wf1 = wf + 65536;
  const u16* wf2 = wf + 81920;
  const float* bias2 = (const float*)(wf + 98304);

  int tid = threadIdx.x, wg = tid >> 6, lane = tid & 63;
  int win = blockIdx.x;
  int d0 = (win >> 8) << 2, h0 = ((win >> 4) & 15) << 2, w0 = (win & 15) << 2;
  int tb = wg * 16;
  int c0 = lane & 15, g4 = (lane >> 4) << 2;

  // ---- load own rows + LN1 -> hs (bf16, swizzled). Own rows: no barrier. ----
  {
    float gv = ln1g[lane], bb = ln1b[lane];
    #pragma unroll
    for (int j = 0; j < 16; ++j){
      int l = tb + j;
      int gd = d0 + (l >> 4), gh = h0 + ((l >> 2) & 3), gw = w0 + (l & 3);
      float v = x[((gd * 64 + gh) * 64 + gw) * 64 + lane];
      float mn = wred_sum(v) * 0.015625f;
      float dv = v - mn;
      float var = wred_sum(dv * dv) * 0.015625f;
      float n = dv * rsqrtf(var + 1e-5f) * gv + bb;
      hs[l * 64 + (lane ^ ((l & 7) << 3))] = f2b(n);
    }
  }

  f32x4 oacc[4];
  #pragma unroll
  for (int ct = 0; ct < 4; ++ct){
    float b0 = bias2[ct * 16 + c0];
    oacc[ct] = (f32x4){b0, b0, b0, b0};
  }

  for (int hh = 0; hh < 4; ++hh){
    // ---- Q/K/V' projection: three sequential passes (low reg pressure) ----
    #pragma unroll
    for (int m = 0; m < 3; ++m){
      f32x4 acc[4];
      #pragma unroll
      for (int ct = 0; ct < 4; ++ct){
        float bb = (m == 0) ? bq[hh * 64 + ct * 16 + c0]
                 : (m == 1) ? bk[hh * 64 + ct * 16 + c0] : 0.f;
        acc[ct] = (f32x4){bb, bb, bb, bb};
      }
      #pragma unroll
      for (int kk = 0; kk < 2; ++kk){
        bf16x8 a = ldfrag<64>(hs, tb, kk * 32, lane);
        const u16* base = wfq + m * 16384 + ((hh * 2 + kk) * 4) * 512 + lane * 8;
        #pragma unroll
        for (int ct = 0; ct < 4; ++ct)
          acc[ct] = __builtin_amdgcn_mfma_f32_16x16x32_bf16(
              a, *(const bf16x8*)(base + ct * 512), acc[ct], 0, 0, 0);
      }
      if (m == 0){
        #pragma unroll
        for (int ct = 0; ct < 4; ++ct) stfrag<64>(qs, tb, ct * 16, acc[ct], 0.125f, lane);
      } else if (m == 1){
        #pragma unroll
        for (int ct = 0; ct < 4; ++ct) stfrag<64>(ks, tb, ct * 16, acc[ct], 1.0f, lane);
      } else {
        #pragma unroll
        for (int ct = 0; ct < 4; ++ct) stfragT(vt, tb, ct * 16, acc[ct], lane);  // V'^T [c][m]
      }
    }
    __syncthreads();   // ks/vt read cross-wave

    // ---- att = Q K^T  (Q fully consumed from qs before P overwrites it) ----
    f32x4 att[4];
    #pragma unroll
    for (int ct = 0; ct < 4; ++ct) att[ct] = (f32x4){0.f, 0.f, 0.f, 0.f};
    #pragma unroll
    for (int kk = 0; kk < 2; ++kk){
      bf16x8 a = ldfrag<64>(qs, tb, kk * 32, lane);
      #pragma unroll
      for (int ct = 0; ct < 4; ++ct)
        att[ct] = __builtin_amdgcn_mfma_f32_16x16x32_bf16(
            a, ldfrag<64>(ks, ct * 16, kk * 32, lane), att[ct], 0, 0, 0);
    }

    // ---- in-register softmax over m (DPP 16-lane reductions) ----
    #pragma unroll
    for (int r = 0; r < 4; ++r){
      float m0 = fmaxf(fmaxf(att[0][r], att[1][r]), fmaxf(att[2][r], att[3][r]));
      m0 = grp16_max(m0);
      float e0 = __expf(att[0][r] - m0), e1 = __expf(att[1][r] - m0);
      float e2 = __expf(att[2][r] - m0), e3 = __expf(att[3][r] - m0);
      float s = grp16_sum(e0 + e1 + e2 + e3);
      float inv = 1.0f / s;
      att[0][r] = e0 * inv; att[1][r] = e1 * inv;
      att[2][r] = e2 * inv; att[3][r] = e3 * inv;
    }
    #pragma unroll
    for (int ct = 0; ct < 4; ++ct) stfrag<64>(qs, tb, ct * 16, att[ct], 1.0f, lane);  // P -> qs

    // ---- oacc += P V'  (out-proj folded into V'; fp32 accumulate, no LDS round-trip) ----
    #pragma unroll
    for (int kk = 0; kk < 2; ++kk){
      bf16x8 a = ldfrag<64>(qs, tb, kk * 32, lane);
      #pragma unroll
      for (int ct = 0; ct < 4; ++ct)
        oacc[ct] = __builtin_amdgcn_mfma_f32_16x16x32_bf16(
            a, ldfrag<64>(vt, ct * 16, kk * 32, lane), oacc[ct], 0, 0, 0);
    }
    __syncthreads();   // before next head overwrites ks/vt (and before FFN LDS reuse)
  }

  // ======== fused x2 + LN2 + FFN (wave-private rows from here: no barriers) ========
  {
    float g2[4], b2l[4];
    #pragma unroll
    for (int ct = 0; ct < 4; ++ct){
      g2[ct] = ln2g[ct * 16 + c0];
      b2l[ct] = ln2b[ct * 16 + c0];
    }
    #pragma unroll
    for (int r = 0; r < 4; ++r){
      float v0 = 2.0f * oacc[0][r], v1 = 2.0f * oacc[1][r];
      float v2 = 2.0f * oacc[2][r], v3 = 2.0f * oacc[3][r];
      float s = grp16_sum(v0 + v1 + v2 + v3);
      float mn = s * 0.015625f;
      float d0f = v0 - mn, d1 = v1 - mn, d2 = v2 - mn, d3 = v3 - mn;
      float q = grp16_sum(d0f*d0f + d1*d1 + d2*d2 + d3*d3);
      float rs = rsqrtf(q * 0.015625f + 1e-5f);
      int row = tb + g4 + r;
      hs[row * 64 + ((0 * 16 + c0) ^ ((row & 7) << 3))] = f2b(d0f * rs * g2[0] + b2l[0]);
      hs[row * 64 + ((1 * 16 + c0) ^ ((row & 7) << 3))] = f2b(d1 * rs * g2[1] + b2l[1]);
      hs[row * 64 + ((2 * 16 + c0) ^ ((row & 7) << 3))] = f2b(d2 * rs * g2[2] + b2l[2]);
      hs[row * 64 + ((3 * 16 + c0) ^ ((row & 7) << 3))] = f2b(d3 * rs * g2[3] + b2l[3]);
    }
  }

  // ---- GEMM1: [16,64] x [64,256] -> y1 (GELU, bf16) ----
  // y1 col-block cb (64 cols) lives in buffer cb at this wave's own rows tb..tb+15.
  // Preload both hs A-fragments BEFORE y1 overwrites the hs slice.
  {
    bf16x8 a0 = ldfrag<64>(hs, tb, 0, lane);
    bf16x8 a1 = ldfrag<64>(hs, tb, 32, lane);
    #pragma unroll
    for (int half = 0; half < 2; ++half){
      f32x4 acc1[8];
      #pragma unroll
      for (int nt = 0; nt < 8; ++nt){
        float bb = b1[(half * 8 + nt) * 16 + c0];
        acc1[nt] = (f32x4){bb, bb, bb, bb};
      }
      const u16* base0 = wf1 + half * 8 * 512 + lane * 8;
      #pragma unroll
      for (int nt = 0; nt < 8; ++nt)
        acc1[nt] = __builtin_amdgcn_mfma_f32_16x16x32_bf16(
            a0, *(const bf16x8*)(base0 + nt * 512), acc1[nt], 0, 0, 0);
      #pragma unroll
      for (int nt = 0; nt < 8; ++nt)
        acc1[nt] = __builtin_amdgcn_mfma_f32_16x16x32_bf16(
            a1, *(const bf16x8*)(base0 + 16 * 512 + nt * 512), acc1[nt], 0, 0, 0);
      #pragma unroll
      for (int nt = 0; nt < 8; ++nt){
        f32x4 v = acc1[nt];
        f32x4 y;
        #pragma unroll
        for (int r = 0; r < 4; ++r) y[r] = gelu(v[r]);
        int gnt = half * 8 + nt;                 // global col tile 0..15
        stfrag<64>(sh + (gnt >> 2) * 4096, tb, (gnt & 3) * 16, y, 1.0f, lane);
      }
    }
  }

  // ---- GEMM2: [16,256] x [256,64] -> out (fp32, merged voxel layout) ----
  {
    f32x4 acc2[4];
    #pragma unroll
    for (int nt = 0; nt < 4; ++nt){
      float bb = b2[nt * 16 + c0];
      acc2[nt] = (f32x4){bb, bb, bb, bb};
    }
    #pragma unroll
    for (int kk = 0; kk < 8; ++kk){
      bf16x8 a = ldfrag<64>(sh + (kk >> 1) * 4096, tb, (kk & 1) * 32, lane);
      const u16* base = wf2 + kk * 4 * 512 + lane * 8;
      #pragma unroll
      for (int nt = 0; nt < 4; ++nt)
        acc2[nt] = __builtin_amdgcn_mfma_f32_16x16x32_bf16(
            a, *(const bf16x8*)(base + nt * 512), acc2[nt], 0, 0, 0);
    }
    #pragma unroll
    for (int r = 0; r < 4; ++r){
      int l = tb + g4 + r;
      int gd = d0 + (l >> 4), gh = h0 + ((l >> 2) & 3), gw = w0 + (l & 3);
      float* orow = out + ((gd * 64 + gh) * 64 + gw) * 64;
      #pragma unroll
      for (int nt = 0; nt < 4; ++nt)
        orow[nt * 16 + c0] = acc2[nt][r];
    }
  }
}

extern "C" void kernel_launch(void* const* d_in, const int* in_sizes, int n_in,
                              void* d_out, int out_size, void* d_ws, size_t ws_size,
                              hipStream_t stream){
  const float* x    = (const float*)d_in[0];
  const float* ln1g = (const float*)d_in[1];
  const float* ln1b = (const float*)d_in[2];
  const float* wq   = (const float*)d_in[3];
  const float* bq   = (const float*)d_in[4];
  const float* wk   = (const float*)d_in[5];
  const float* bk   = (const float*)d_in[6];
  const float* wv   = (const float*)d_in[7];
  const float* bv   = (const float*)d_in[8];
  const float* wo   = (const float*)d_in[9];
  const float* bo   = (const float*)d_in[10];
  const float* ln2g = (const float*)d_in[11];
  const float* ln2b = (const float*)d_in[12];
  const float* w1   = (const float*)d_in[13];
  const float* b1   = (const float*)d_in[14];
  const float* w2   = (const float*)d_in[15];
  const float* b2   = (const float*)d_in[16];

  u16* wf = (u16*)d_ws;     // 192KB bf16 weight fragments + 256B fp32 bias2
  float* out = (float*)d_out;

  k_prep<<<385, 256, 0, stream>>>(wq, wk, wv, wo, w1, w2, bv, bo, wf);
  k_mega<<<NWIN, 256, 0, stream>>>(x, ln1g, ln1b, bq, bk,
                                   ln2g, ln2b, b1, b2, wf, out);
}

// Round 17
// 148.592 us; speedup vs baseline: 1.7676x; 1.0394x over previous
//
#include <hip/hip_runtime.h>
#include <math.h>

#define NWIN 4096    // (64/4)^3 windows

typedef unsigned short u16;
typedef __bf16 bf16;
typedef __attribute__((ext_vector_type(8))) __bf16 bf16x8;
typedef __attribute__((ext_vector_type(4))) float f32x4;

__device__ __forceinline__ u16 f2b(float f){
  return __builtin_bit_cast(u16, (bf16)f);
}

// ---- DPP cross-lane (VALU-pipe, ~2cyc vs ds_swizzle ~30cyc) ----
// quad_perm xor1 = 0xB1; xor2 = 0x4E; row_ror:4 = 0x124, row_ror:8 = 0x128;
// ROW_BCAST15 = 0x142 (lane15->16..31, lane47->48..63); ROW_BCAST31 = 0x143 (lane31->32..63)
template<int CTRL>
__device__ __forceinline__ float dppf(float v){
  return __builtin_bit_cast(float, __builtin_amdgcn_update_dpp(
      0, __builtin_bit_cast(int, v), CTRL, 0xF, 0xF, false));
}
__device__ __forceinline__ float grp16_sum(float v){
  v += dppf<0xB1>(v);
  v += dppf<0x4E>(v);
  v += dppf<0x124>(v);
  v += dppf<0x128>(v);
  return v;
}
__device__ __forceinline__ float grp16_max(float v){
  v = fmaxf(v, dppf<0xB1>(v));
  v = fmaxf(v, dppf<0x4E>(v));
  v = fmaxf(v, dppf<0x124>(v));
  v = fmaxf(v, dppf<0x128>(v));
  return v;
}
// full 64-lane sum, pure VALU: grp16 + row_bcast15/31 accumulate into lanes 48-63;
// readlane 63 broadcasts via SGPR. Same partial-sum pairing as xor16+xor32 (commuted)
// -> bit-identical.
__device__ __forceinline__ float wred_sum(float v){
  v = grp16_sum(v);
  v += dppf<0x142>(v);   // ROW_BCAST15
  v += dppf<0x143>(v);   // ROW_BCAST31: lane63 = total
  return __builtin_bit_cast(float,
      __builtin_amdgcn_readlane(__builtin_bit_cast(int, v), 63));
}
// GELU, sigmoid form: v*sigmoid(1.5957692*(v+0.044715 v^3)).
__device__ __forceinline__ float gelu(float v){
  float v2 = v * v;
  float inner = fmaf(v2, -0.07135806f, -1.5957692f);
  float e = __expf(v * inner);
  return v * __builtin_amdgcn_rcpf(1.0f + e);
}

// ---- LDS fragment helpers: bf16 tiles, XOR-swizzled (col ^ ((row&7)<<3)) ----
template<int STRIDE>
__device__ __forceinline__ bf16x8 ldfrag(const u16* m, int rowbase, int colbase, int lane){
  int row = rowbase + (lane & 15);
  int col = colbase + ((lane >> 4) << 3);
  return *(const bf16x8*)&m[row * STRIDE + (col ^ ((row & 7) << 3))];
}
template<int STRIDE>
__device__ __forceinline__ void stfrag(u16* m, int rowbase, int colbase, f32x4 v, float s, int lane){
  int col = colbase + (lane & 15);
  int r0  = rowbase + ((lane >> 4) << 2);
  #pragma unroll
  for (int r = 0; r < 4; ++r){
    int row = r0 + r;
    m[row * STRIDE + (col ^ ((row & 7) << 3))] = f2b(v[r] * s);
  }
}
// store transposed: element (row,col) -> m[col][row]
__device__ __forceinline__ void stfragT(u16* m, int rowbase, int colbase, f32x4 v, int lane){
  int col = colbase + (lane & 15);
  int r0  = rowbase + ((lane >> 4) << 2);
  #pragma unroll
  for (int r = 0; r < 4; ++r){
    int row = r0 + r;
    m[col * 64 + (row ^ ((col & 7) << 3))] = f2b(v[r]);
  }
}

// ---------------- prep: weights -> bf16 B-fragment order in d_ws ----------------
// wfq: [mat3][head4][kk2][ct4][lane64][8]   49152 u16  (mat2 = U_h = Wv_h @ Wo_h, FOLDED)
// (49152..65536 unused — old wfo slot, kept for layout stability)
// wf1: [kk2][nt16][lane64][8]               16384 u16 @ 65536
// wf2: [kk8][nt4][lane64][8]                16384 u16 @ 81920
// bias2: 64 fp32 @ u16-offset 98304         (bo + sum_h bv_h @ Wo_h)
__global__ __launch_bounds__(256) void k_prep(
    const float* __restrict__ wq, const float* __restrict__ wk,
    const float* __restrict__ wv, const float* __restrict__ wo,
    const float* __restrict__ w1, const float* __restrict__ w2,
    const float* __restrict__ bv, const float* __restrict__ bo,
    u16* __restrict__ wfq){
  int idx = blockIdx.x * 256 + threadIdx.x;
  if (idx >= 98368) return;
  int e = idx & 7, lane = (idx >> 3) & 63;
  if (idx < 49152){
    int ct = (idx >> 9) & 3, kk = (idx >> 11) & 1, hh = (idx >> 12) & 3, m = idx >> 14;
    int c = kk * 32 + ((lane >> 4) << 3) + e;
    int d = (ct << 4) + (lane & 15);
    if (m < 2){
      const float* W = (m == 0) ? wq : wk;
      wfq[idx] = f2b(W[(c * 4 + hh) * 64 + d]);
    } else {
      // U_h[c][d] = sum_k Wv[(c,hh),k] * Wo[(hh,k),d]
      float s = 0.f;
      for (int k = 0; k < 64; ++k)
        s += wv[(c * 4 + hh) * 64 + k] * wo[(hh * 64 + k) * 64 + d];
      wfq[idx] = f2b(s);
    }
  } else if (idx < 65536){
    // old wfo slot: unused after the fold
  } else if (idx < 81920){
    int j = idx - 65536;
    int nt = (j >> 9) & 15, kk = (j >> 13) & 1;
    int c = kk * 32 + ((lane >> 4) << 3) + e;
    int f = nt * 16 + (lane & 15);
    wfq[idx] = f2b(w1[c * 256 + f]);
  } else if (idx < 98304){
    int j = idx - 81920;
    int nt = (j >> 9) & 3, kk = (j >> 11) & 7;
    int f = kk * 32 + ((lane >> 4) << 3) + e;
    int c = nt * 16 + (lane & 15);
    wfq[idx] = f2b(w2[f * 64 + c]);
  } else {
    int c = idx - 98304;          // 0..63
    float s = bo[c];
    for (int k = 0; k < 256; ++k) // hh*64+d
      s += bv[k] * wo[k * 64 + c];
    ((float*)(wfq + 98304))[c] = s;
  }
}

// ------- fused LN1 + window MHA (out-proj FOLDED into V) + x2 + LN2 + FFN -------
// ROUND 16 CHAMPION + full-DPP wred_sum (row_bcast15/31 + readlane replace the
// last 64 LDS-pipe shuffles per wave in LN1). One block (4 waves) per window;
// wave owns 16 token rows. 32KB LDS.
__global__ __launch_bounds__(256, 4) void k_mega(
    const float* __restrict__ x,
    const float* __restrict__ ln1g, const float* __restrict__ ln1b,
    const float* __restrict__ bq, const float* __restrict__ bk,
    const float* __restrict__ ln2g, const float* __restrict__ ln2b,
    const float* __restrict__ b1, const float* __restrict__ b2,
    const u16* __restrict__ wf,
    float* __restrict__ out){
  __shared__ alignas(16) u16 sh[16384];   // 32KB: 4 x [64][64] bf16 buffers
  u16* hs = sh;           // LN1(x); later LN2 result; later y1 col-block 0 (per-wave rows)
  u16* qs = sh + 4096;    // Q -> P (wave-private rows); later y1 cb1
  u16* ks = sh + 8192;    // K (cross-wave); later y1 cb2
  u16* vt = sh + 12288;   // V'^T (cross-wave); later y1 cb3
  const u16* wfq = wf;
  const u16* wf1 = wf + 65536;
  const u16* wf2 = wf + 81920;
  const float* bias2 = (const float*)(wf + 98304);

  int tid = threadIdx.x, wg = tid >> 6, lane = tid & 63;
  int win = blockIdx.x;
  int d0 = (win >> 8) << 2, h0 = ((win >> 4) & 15) << 2, w0 = (win & 15) << 2;
  int tb = wg * 16;
  int c0 = lane & 15, g4 = (lane >> 4) << 2;

  // ---- load own rows + LN1 -> hs (bf16, swizzled). Own rows: no barrier. ----
  {
    float gv = ln1g[lane], bb = ln1b[lane];
    #pragma unroll
    for (int j = 0; j < 16; ++j){
      int l = tb + j;
      int gd = d0 + (l >> 4), gh = h0 + ((l >> 2) & 3), gw = w0 + (l & 3);
      float v = x[((gd * 64 + gh) * 64 + gw) * 64 + lane];
      float mn = wred_sum(v) * 0.015625f;
      float dv = v - mn;
      float var = wred_sum(dv * dv) * 0.015625f;
      float n = dv * rsqrtf(var + 1e-5f) * gv + bb;
      hs[l * 64 + (lane ^ ((l & 7) << 3))] = f2b(n);
    }
  }

  f32x4 oacc[4];
  #pragma unroll
  for (int ct = 0; ct < 4; ++ct){
    float b0 = bias2[ct * 16 + c0];
    oacc[ct] = (f32x4){b0, b0, b0, b0};
  }

  for (int hh = 0; hh < 4; ++hh){
    // ---- Q/K/V' projection: three sequential passes (low reg pressure) ----
    #pragma unroll
    for (int m = 0; m < 3; ++m){
      f32x4 acc[4];
      #pragma unroll
      for (int ct = 0; ct < 4; ++ct){
        float bb = (m == 0) ? bq[hh * 64 + ct * 16 + c0]
                 : (m == 1) ? bk[hh * 64 + ct * 16 + c0] : 0.f;
        acc[ct] = (f32x4){bb, bb, bb, bb};
      }
      #pragma unroll
      for (int kk = 0; kk < 2; ++kk){
        bf16x8 a = ldfrag<64>(hs, tb, kk * 32, lane);
        const u16* base = wfq + m * 16384 + ((hh * 2 + kk) * 4) * 512 + lane * 8;
        #pragma unroll
        for (int ct = 0; ct < 4; ++ct)
          acc[ct] = __builtin_amdgcn_mfma_f32_16x16x32_bf16(
              a, *(const bf16x8*)(base + ct * 512), acc[ct], 0, 0, 0);
      }
      if (m == 0){
        #pragma unroll
        for (int ct = 0; ct < 4; ++ct) stfrag<64>(qs, tb, ct * 16, acc[ct], 0.125f, lane);
      } else if (m == 1){
        #pragma unroll
        for (int ct = 0; ct < 4; ++ct) stfrag<64>(ks, tb, ct * 16, acc[ct], 1.0f, lane);
      } else {
        #pragma unroll
        for (int ct = 0; ct < 4; ++ct) stfragT(vt, tb, ct * 16, acc[ct], lane);  // V'^T [c][m]
      }
    }
    __syncthreads();   // ks/vt read cross-wave

    // ---- att = Q K^T  (Q fully consumed from qs before P overwrites it) ----
    f32x4 att[4];
    #pragma unroll
    for (int ct = 0; ct < 4; ++ct) att[ct] = (f32x4){0.f, 0.f, 0.f, 0.f};
    #pragma unroll
    for (int kk = 0; kk < 2; ++kk){
      bf16x8 a = ldfrag<64>(qs, tb, kk * 32, lane);
      #pragma unroll
      for (int ct = 0; ct < 4; ++ct)
        att[ct] = __builtin_amdgcn_mfma_f32_16x16x32_bf16(
            a, ldfrag<64>(ks, ct * 16, kk * 32, lane), att[ct], 0, 0, 0);
    }

    // ---- in-register softmax over m (DPP 16-lane reductions) ----
    #pragma unroll
    for (int r = 0; r < 4; ++r){
      float m0 = fmaxf(fmaxf(att[0][r], att[1][r]), fmaxf(att[2][r], att[3][r]));
      m0 = grp16_max(m0);
      float e0 = __expf(att[0][r] - m0), e1 = __expf(att[1][r] - m0);
      float e2 = __expf(att[2][r] - m0), e3 = __expf(att[3][r] - m0);
      float s = grp16_sum(e0 + e1 + e2 + e3);
      float inv = 1.0f / s;
      att[0][r] = e0 * inv; att[1][r] = e1 * inv;
      att[2][r] = e2 * inv; att[3][r] = e3 * inv;
    }
    #pragma unroll
    for (int ct = 0; ct < 4; ++ct) stfrag<64>(qs, tb, ct * 16, att[ct], 1.0f, lane);  // P -> qs

    // ---- oacc += P V'  (out-proj folded into V'; fp32 accumulate, no LDS round-trip) ----
    #pragma unroll
    for (int kk = 0; kk < 2; ++kk){
      bf16x8 a = ldfrag<64>(qs, tb, kk * 32, lane);
      #pragma unroll
      for (int ct = 0; ct < 4; ++ct)
        oacc[ct] = __builtin_amdgcn_mfma_f32_16x16x32_bf16(
            a, ldfrag<64>(vt, ct * 16, kk * 32, lane), oacc[ct], 0, 0, 0);
    }
    __syncthreads();   // before next head overwrites ks/vt (and before FFN LDS reuse)
  }

  // ======== fused x2 + LN2 + FFN (wave-private rows from here: no barriers) ========
  {
    float g2[4], b2l[4];
    #pragma unroll
    for (int ct = 0; ct < 4; ++ct){
      g2[ct] = ln2g[ct * 16 + c0];
      b2l[ct] = ln2b[ct * 16 + c0];
    }
    #pragma unroll
    for (int r = 0; r < 4; ++r){
      float v0 = 2.0f * oacc[0][r], v1 = 2.0f * oacc[1][r];
      float v2 = 2.0f * oacc[2][r], v3 = 2.0f * oacc[3][r];
      float s = grp16_sum(v0 + v1 + v2 + v3);
      float mn = s * 0.015625f;
      float d0f = v0 - mn, d1 = v1 - mn, d2 = v2 - mn, d3 = v3 - mn;
      float q = grp16_sum(d0f*d0f + d1*d1 + d2*d2 + d3*d3);
      float rs = rsqrtf(q * 0.015625f + 1e-5f);
      int row = tb + g4 + r;
      hs[row * 64 + ((0 * 16 + c0) ^ ((row & 7) << 3))] = f2b(d0f * rs * g2[0] + b2l[0]);
      hs[row * 64 + ((1 * 16 + c0) ^ ((row & 7) << 3))] = f2b(d1 * rs * g2[1] + b2l[1]);
      hs[row * 64 + ((2 * 16 + c0) ^ ((row & 7) << 3))] = f2b(d2 * rs * g2[2] + b2l[2]);
      hs[row * 64 + ((3 * 16 + c0) ^ ((row & 7) << 3))] = f2b(d3 * rs * g2[3] + b2l[3]);
    }
  }

  // ---- GEMM1: [16,64] x [64,256] -> y1 (GELU, bf16) ----
  // y1 col-block cb (64 cols) lives in buffer cb at this wave's own rows tb..tb+15.
  // Preload both hs A-fragments BEFORE y1 overwrites the hs slice.
  {
    bf16x8 a0 = ldfrag<64>(hs, tb, 0, lane);
    bf16x8 a1 = ldfrag<64>(hs, tb, 32, lane);
    #pragma unroll
    for (int half = 0; half < 2; ++half){
      f32x4 acc1[8];
      #pragma unroll
      for (int nt = 0; nt < 8; ++nt){
        float bb = b1[(half * 8 + nt) * 16 + c0];
        acc1[nt] = (f32x4){bb, bb, bb, bb};
      }
      const u16* base0 = wf1 + half * 8 * 512 + lane * 8;
      #pragma unroll
      for (int nt = 0; nt < 8; ++nt)
        acc1[nt] = __builtin_amdgcn_mfma_f32_16x16x32_bf16(
            a0, *(const bf16x8*)(base0 + nt * 512), acc1[nt], 0, 0, 0);
      #pragma unroll
      for (int nt = 0; nt < 8; ++nt)
        acc1[nt] = __builtin_amdgcn_mfma_f32_16x16x32_bf16(
            a1, *(const bf16x8*)(base0 + 16 * 512 + nt * 512), acc1[nt], 0, 0, 0);
      #pragma unroll
      for (int nt = 0; nt < 8; ++nt){
        f32x4 v = acc1[nt];
        f32x4 y;
        #pragma unroll
        for (int r = 0; r < 4; ++r) y[r] = gelu(v[r]);
        int gnt = half * 8 + nt;                 // global col tile 0..15
        stfrag<64>(sh + (gnt >> 2) * 4096, tb, (gnt & 3) * 16, y, 1.0f, lane);
      }
    }
  }

  // ---- GEMM2: [16,256] x [256,64] -> out (fp32, merged voxel layout) ----
  {
    f32x4 acc2[4];
    #pragma unroll
    for (int nt = 0; nt < 4; ++nt){
      float bb = b2[nt * 16 + c0];
      acc2[nt] = (f32x4){bb, bb, bb, bb};
    }
    #pragma unroll
    for (int kk = 0; kk < 8; ++kk){
      bf16x8 a = ldfrag<64>(sh + (kk >> 1) * 4096, tb, (kk & 1) * 32, lane);
      const u16* base = wf2 + kk * 4 * 512 + lane * 8;
      #pragma unroll
      for (int nt = 0; nt < 4; ++nt)
        acc2[nt] = __builtin_amdgcn_mfma_f32_16x16x32_bf16(
            a, *(const bf16x8*)(base + nt * 512), acc2[nt], 0, 0, 0);
    }
    #pragma unroll
    for (int r = 0; r < 4; ++r){
      int l = tb + g4 + r;
      int gd = d0 + (l >> 4), gh = h0 + ((l >> 2) & 3), gw = w0 + (l & 3);
      float* orow = out + ((gd * 64 + gh) * 64 + gw) * 64;
      #pragma unroll
      for (int nt = 0; nt < 4; ++nt)
        orow[nt * 16 + c0] = acc2[nt][r];
    }
  }
}

extern "C" void kernel_launch(void* const* d_in, const int* in_sizes, int n_in,
                              void* d_out, int out_size, void* d_ws, size_t ws_size,
                              hipStream_t stream){
  const float* x    = (const float*)d_in[0];
  const float* ln1g = (const float*)d_in[1];
  const float* ln1b = (const float*)d_in[2];
  const float* wq   = (const float*)d_in[3];
  const float* bq   = (const float*)d_in[4];
  const float* wk   = (const float*)d_in[5];
  const float* bk   = (const float*)d_in[6];
  const float* wv   = (const float*)d_in[7];
  const float* bv   = (const float*)d_in[8];
  const float* wo   = (const float*)d_in[9];
  const float* bo   = (const float*)d_in[10];
  const float* ln2g = (const float*)d_in[11];
  const float* ln2b = (const float*)d_in[12];
  const float* w1   = (const float*)d_in[13];
  const float* b1   = (const float*)d_in[14];
  const float* w2   = (const float*)d_in[15];
  const float* b2   = (const float*)d_in[16];

  u16* wf = (u16*)d_ws;     // 192KB bf16 weight fragments + 256B fp32 bias2
  float* out = (float*)d_out;

  k_prep<<<385, 256, 0, stream>>>(wq, wk, wv, wo, w1, w2, bv, bo, wf);
  k_mega<<<NWIN, 256, 0, stream>>>(x, ln1g, ln1b, bq, bk,
                                   ln2g, ln2b, b1, b2, wf, out);
}

// Round 18
// 140.728 us; speedup vs baseline: 1.8664x; 1.0559x over previous
//
#include <hip/hip_runtime.h>
#include <math.h>

#define NWIN 4096    // (64/4)^3 windows

typedef unsigned short u16;
typedef unsigned int u32;
typedef __bf16 bf16;
typedef __attribute__((ext_vector_type(8))) __bf16 bf16x8;
typedef __attribute__((ext_vector_type(4))) float f32x4;

__device__ __forceinline__ u16 f2b(float f){
  return __builtin_bit_cast(u16, (bf16)f);
}
__device__ __forceinline__ u32 pack2(float lo, float hi){
  return ((u32)f2b(hi) << 16) | (u32)f2b(lo);
}

// ---- DPP cross-lane (VALU-pipe, ~2cyc vs ds_swizzle ~30cyc) ----
// quad_perm xor1 = 0xB1; xor2 = 0x4E; row_ror:4 = 0x124, row_ror:8 = 0x128
template<int CTRL>
__device__ __forceinline__ float dppf(float v){
  return __builtin_bit_cast(float, __builtin_amdgcn_update_dpp(
      0, __builtin_bit_cast(int, v), CTRL, 0xF, 0xF, false));
}
__device__ __forceinline__ float grp16_sum(float v){
  v += dppf<0xB1>(v);
  v += dppf<0x4E>(v);
  v += dppf<0x124>(v);
  v += dppf<0x128>(v);
  return v;
}
__device__ __forceinline__ float grp16_max(float v){
  v = fmaxf(v, dppf<0xB1>(v));
  v = fmaxf(v, dppf<0x4E>(v));
  v = fmaxf(v, dppf<0x124>(v));
  v = fmaxf(v, dppf<0x128>(v));
  return v;
}
// GELU, sigmoid form: v*sigmoid(1.5957692*(v+0.044715 v^3)).
__device__ __forceinline__ float gelu(float v){
  float v2 = v * v;
  float inner = fmaf(v2, -0.07135806f, -1.5957692f);
  float e = __expf(v * inner);
  return v * __builtin_amdgcn_rcpf(1.0f + e);
}

// ---- LDS fragment helpers: bf16 tiles, XOR-swizzled (col ^ ((row&7)<<3)) ----
template<int STRIDE>
__device__ __forceinline__ bf16x8 ldfrag(const u16* m, int rowbase, int colbase, int lane){
  int row = rowbase + (lane & 15);
  int col = colbase + ((lane >> 4) << 3);
  return *(const bf16x8*)&m[row * STRIDE + (col ^ ((row & 7) << 3))];
}
template<int STRIDE>
__device__ __forceinline__ void stfrag(u16* m, int rowbase, int colbase, f32x4 v, float s, int lane){
  int col = colbase + (lane & 15);
  int r0  = rowbase + ((lane >> 4) << 2);
  #pragma unroll
  for (int r = 0; r < 4; ++r){
    int row = r0 + r;
    m[row * STRIDE + (col ^ ((row & 7) << 3))] = f2b(v[r] * s);
  }
}
// store transposed: element (row,col) -> m[col][row]
__device__ __forceinline__ void stfragT(u16* m, int rowbase, int colbase, f32x4 v, int lane){
  int col = colbase + (lane & 15);
  int r0  = rowbase + ((lane >> 4) << 2);
  #pragma unroll
  for (int r = 0; r < 4; ++r){
    int row = r0 + r;
    m[col * 64 + (row ^ ((col & 7) << 3))] = f2b(v[r]);
  }
}

// ---------------- prep: weights -> bf16 B-fragment order in d_ws ----------------
// wfq: [mat3][head4][kk2][ct4][lane64][8]   49152 u16  (mat2 = U_h = Wv_h @ Wo_h, FOLDED)
// (49152..65536 unused — old wfo slot, kept for layout stability)
// wf1: [kk2][nt16][lane64][8]               16384 u16 @ 65536
// wf2: [kk8][nt4][lane64][8]                16384 u16 @ 81920
// bias2: 64 fp32 @ u16-offset 98304         (bo + sum_h bv_h @ Wo_h)
__global__ __launch_bounds__(256) void k_prep(
    const float* __restrict__ wq, const float* __restrict__ wk,
    const float* __restrict__ wv, const float* __restrict__ wo,
    const float* __restrict__ w1, const float* __restrict__ w2,
    const float* __restrict__ bv, const float* __restrict__ bo,
    u16* __restrict__ wfq){
  int idx = blockIdx.x * 256 + threadIdx.x;
  if (idx >= 98368) return;
  int e = idx & 7, lane = (idx >> 3) & 63;
  if (idx < 49152){
    int ct = (idx >> 9) & 3, kk = (idx >> 11) & 1, hh = (idx >> 12) & 3, m = idx >> 14;
    int c = kk * 32 + ((lane >> 4) << 3) + e;
    int d = (ct << 4) + (lane & 15);
    if (m < 2){
      const float* W = (m == 0) ? wq : wk;
      wfq[idx] = f2b(W[(c * 4 + hh) * 64 + d]);
    } else {
      // U_h[c][d] = sum_k Wv[(c,hh),k] * Wo[(hh,k),d]
      float s = 0.f;
      for (int k = 0; k < 64; ++k)
        s += wv[(c * 4 + hh) * 64 + k] * wo[(hh * 64 + k) * 64 + d];
      wfq[idx] = f2b(s);
    }
  } else if (idx < 65536){
    // old wfo slot: unused after the fold
  } else if (idx < 81920){
    int j = idx - 65536;
    int nt = (j >> 9) & 15, kk = (j >> 13) & 1;
    int c = kk * 32 + ((lane >> 4) << 3) + e;
    int f = nt * 16 + (lane & 15);
    wfq[idx] = f2b(w1[c * 256 + f]);
  } else if (idx < 98304){
    int j = idx - 81920;
    int nt = (j >> 9) & 3, kk = (j >> 11) & 7;
    int f = kk * 32 + ((lane >> 4) << 3) + e;
    int c = nt * 16 + (lane & 15);
    wfq[idx] = f2b(w2[f * 64 + c]);
  } else {
    int c = idx - 98304;          // 0..63
    float s = bo[c];
    for (int k = 0; k < 256; ++k) // hh*64+d
      s += bv[k] * wo[k * 64 + c];
    ((float*)(wfq + 98304))[c] = s;
  }
}

// ------- fused LN1 + window MHA (out-proj FOLDED into V) + x2 + LN2 + FFN -------
// ROUND 17 CHAMPION + vectorized LN1 (lane = 4 channels via float4; per-row
// reduce is a single 16-lane DPP tree — no cross-group step, no readlane).
// One block (4 waves) per window; wave owns 16 token rows. 32KB LDS.
__global__ __launch_bounds__(256, 4) void k_mega(
    const float* __restrict__ x,
    const float* __restrict__ ln1g, const float* __restrict__ ln1b,
    const float* __restrict__ bq, const float* __restrict__ bk,
    const float* __restrict__ ln2g, const float* __restrict__ ln2b,
    const float* __restrict__ b1, const float* __restrict__ b2,
    const u16* __restrict__ wf,
    float* __restrict__ out){
  __shared__ alignas(16) u16 sh[16384];   // 32KB: 4 x [64][64] bf16 buffers
  u16* hs = sh;           // LN1(x); later LN2 result; later y1 col-block 0 (per-wave rows)
  u16* qs = sh + 4096;    // Q -> P (wave-private rows); later y1 cb1
  u16* ks = sh + 8192;    // K (cross-wave); later y1 cb2
  u16* vt = sh + 12288;   // V'^T (cross-wave); later y1 cb3
  const u16* wfq = wf;
  const u16* wf1 = wf + 65536;
  const u16* wf2 = wf + 81920;
  const float* bias2 = (const float*)(wf + 98304);

  int tid = threadIdx.x, wg = tid >> 6, lane = tid & 63;
  int win = blockIdx.x;
  int d0 = (win >> 8) << 2, h0 = ((win >> 4) & 15) << 2, w0 = (win & 15) << 2;
  int tb = wg * 16;
  int c0 = lane & 15, g4 = (lane >> 4) << 2;

  // ---- LN1, vectorized: lane holds 4 channels; each 16-lane DPP row = one token
  //      row; 4 rows per iteration. Own rows only: no barrier. ----
  {
    int c4 = c0 * 4;
    int sub = lane >> 4;
    const float4 g4v = *(const float4*)&ln1g[c4];
    const float4 b4v = *(const float4*)&ln1b[c4];
    #pragma unroll
    for (int i = 0; i < 4; ++i){
      int l = tb + i * 4 + sub;
      int gd = d0 + (l >> 4), gh = h0 + ((l >> 2) & 3), gw = w0 + (l & 3);
      const float4 xv = *(const float4*)&x[(((gd * 64 + gh) * 64 + gw) << 6) + c4];
      float s = grp16_sum(xv.x + xv.y + xv.z + xv.w);
      float mn = s * 0.015625f;
      float e0 = xv.x - mn, e1 = xv.y - mn, e2 = xv.z - mn, e3 = xv.w - mn;
      float q = grp16_sum(e0*e0 + e1*e1 + e2*e2 + e3*e3);
      float rs = rsqrtf(q * 0.015625f + 1e-5f);
      float n0 = e0 * rs * g4v.x + b4v.x;
      float n1 = e1 * rs * g4v.y + b4v.y;
      float n2 = e2 * rs * g4v.z + b4v.z;
      float n3 = e3 * rs * g4v.w + b4v.w;
      // c4 is 4-aligned; XOR swizzle touches bits >=3 -> 8B-aligned uint2 store
      *(uint2*)&hs[l * 64 + (c4 ^ ((l & 7) << 3))] = (uint2){pack2(n0, n1), pack2(n2, n3)};
    }
  }

  f32x4 oacc[4];
  #pragma unroll
  for (int ct = 0; ct < 4; ++ct){
    float b0 = bias2[ct * 16 + c0];
    oacc[ct] = (f32x4){b0, b0, b0, b0};
  }

  for (int hh = 0; hh < 4; ++hh){
    // ---- Q/K/V' projection: three sequential passes (low reg pressure) ----
    #pragma unroll
    for (int m = 0; m < 3; ++m){
      f32x4 acc[4];
      #pragma unroll
      for (int ct = 0; ct < 4; ++ct){
        float bb = (m == 0) ? bq[hh * 64 + ct * 16 + c0]
                 : (m == 1) ? bk[hh * 64 + ct * 16 + c0] : 0.f;
        acc[ct] = (f32x4){bb, bb, bb, bb};
      }
      #pragma unroll
      for (int kk = 0; kk < 2; ++kk){
        bf16x8 a = ldfrag<64>(hs, tb, kk * 32, lane);
        const u16* base = wfq + m * 16384 + ((hh * 2 + kk) * 4) * 512 + lane * 8;
        #pragma unroll
        for (int ct = 0; ct < 4; ++ct)
          acc[ct] = __builtin_amdgcn_mfma_f32_16x16x32_bf16(
              a, *(const bf16x8*)(base + ct * 512), acc[ct], 0, 0, 0);
      }
      if (m == 0){
        #pragma unroll
        for (int ct = 0; ct < 4; ++ct) stfrag<64>(qs, tb, ct * 16, acc[ct], 0.125f, lane);
      } else if (m == 1){
        #pragma unroll
        for (int ct = 0; ct < 4; ++ct) stfrag<64>(ks, tb, ct * 16, acc[ct], 1.0f, lane);
      } else {
        #pragma unroll
        for (int ct = 0; ct < 4; ++ct) stfragT(vt, tb, ct * 16, acc[ct], lane);  // V'^T [c][m]
      }
    }
    __syncthreads();   // ks/vt read cross-wave

    // ---- att = Q K^T  (Q fully consumed from qs before P overwrites it) ----
    f32x4 att[4];
    #pragma unroll
    for (int ct = 0; ct < 4; ++ct) att[ct] = (f32x4){0.f, 0.f, 0.f, 0.f};
    #pragma unroll
    for (int kk = 0; kk < 2; ++kk){
      bf16x8 a = ldfrag<64>(qs, tb, kk * 32, lane);
      #pragma unroll
      for (int ct = 0; ct < 4; ++ct)
        att[ct] = __builtin_amdgcn_mfma_f32_16x16x32_bf16(
            a, ldfrag<64>(ks, ct * 16, kk * 32, lane), att[ct], 0, 0, 0);
    }

    // ---- in-register softmax over m (DPP 16-lane reductions) ----
    #pragma unroll
    for (int r = 0; r < 4; ++r){
      float m0 = fmaxf(fmaxf(att[0][r], att[1][r]), fmaxf(att[2][r], att[3][r]));
      m0 = grp16_max(m0);
      float e0 = __expf(att[0][r] - m0), e1 = __expf(att[1][r] - m0);
      float e2 = __expf(att[2][r] - m0), e3 = __expf(att[3][r] - m0);
      float s = grp16_sum(e0 + e1 + e2 + e3);
      float inv = 1.0f / s;
      att[0][r] = e0 * inv; att[1][r] = e1 * inv;
      att[2][r] = e2 * inv; att[3][r] = e3 * inv;
    }
    #pragma unroll
    for (int ct = 0; ct < 4; ++ct) stfrag<64>(qs, tb, ct * 16, att[ct], 1.0f, lane);  // P -> qs

    // ---- oacc += P V'  (out-proj folded into V'; fp32 accumulate, no LDS round-trip) ----
    #pragma unroll
    for (int kk = 0; kk < 2; ++kk){
      bf16x8 a = ldfrag<64>(qs, tb, kk * 32, lane);
      #pragma unroll
      for (int ct = 0; ct < 4; ++ct)
        oacc[ct] = __builtin_amdgcn_mfma_f32_16x16x32_bf16(
            a, ldfrag<64>(vt, ct * 16, kk * 32, lane), oacc[ct], 0, 0, 0);
    }
    __syncthreads();   // before next head overwrites ks/vt (and before FFN LDS reuse)
  }

  // ======== fused x2 + LN2 + FFN (wave-private rows from here: no barriers) ========
  {
    float g2[4], b2l[4];
    #pragma unroll
    for (int ct = 0; ct < 4; ++ct){
      g2[ct] = ln2g[ct * 16 + c0];
      b2l[ct] = ln2b[ct * 16 + c0];
    }
    #pragma unroll
    for (int r = 0; r < 4; ++r){
      float v0 = 2.0f * oacc[0][r], v1 = 2.0f * oacc[1][r];
      float v2 = 2.0f * oacc[2][r], v3 = 2.0f * oacc[3][r];
      float s = grp16_sum(v0 + v1 + v2 + v3);
      float mn = s * 0.015625f;
      float d0f = v0 - mn, d1 = v1 - mn, d2 = v2 - mn, d3 = v3 - mn;
      float q = grp16_sum(d0f*d0f + d1*d1 + d2*d2 + d3*d3);
      float rs = rsqrtf(q * 0.015625f + 1e-5f);
      int row = tb + g4 + r;
      hs[row * 64 + ((0 * 16 + c0) ^ ((row & 7) << 3))] = f2b(d0f * rs * g2[0] + b2l[0]);
      hs[row * 64 + ((1 * 16 + c0) ^ ((row & 7) << 3))] = f2b(d1 * rs * g2[1] + b2l[1]);
      hs[row * 64 + ((2 * 16 + c0) ^ ((row & 7) << 3))] = f2b(d2 * rs * g2[2] + b2l[2]);
      hs[row * 64 + ((3 * 16 + c0) ^ ((row & 7) << 3))] = f2b(d3 * rs * g2[3] + b2l[3]);
    }
  }

  // ---- GEMM1: [16,64] x [64,256] -> y1 (GELU, bf16) ----
  // y1 col-block cb (64 cols) lives in buffer cb at this wave's own rows tb..tb+15.
  // Preload both hs A-fragments BEFORE y1 overwrites the hs slice.
  {
    bf16x8 a0 = ldfrag<64>(hs, tb, 0, lane);
    bf16x8 a1 = ldfrag<64>(hs, tb, 32, lane);
    #pragma unroll
    for (int half = 0; half < 2; ++half){
      f32x4 acc1[8];
      #pragma unroll
      for (int nt = 0; nt < 8; ++nt){
        float bb = b1[(half * 8 + nt) * 16 + c0];
        acc1[nt] = (f32x4){bb, bb, bb, bb};
      }
      const u16* base0 = wf1 + half * 8 * 512 + lane * 8;
      #pragma unroll
      for (int nt = 0; nt < 8; ++nt)
        acc1[nt] = __builtin_amdgcn_mfma_f32_16x16x32_bf16(
            a0, *(const bf16x8*)(base0 + nt * 512), acc1[nt], 0, 0, 0);
      #pragma unroll
      for (int nt = 0; nt < 8; ++nt)
        acc1[nt] = __builtin_amdgcn_mfma_f32_16x16x32_bf16(
            a1, *(const bf16x8*)(base0 + 16 * 512 + nt * 512), acc1[nt], 0, 0, 0);
      #pragma unroll
      for (int nt = 0; nt < 8; ++nt){
        f32x4 v = acc1[nt];
        f32x4 y;
        #pragma unroll
        for (int r = 0; r < 4; ++r) y[r] = gelu(v[r]);
        int gnt = half * 8 + nt;                 // global col tile 0..15
        stfrag<64>(sh + (gnt >> 2) * 4096, tb, (gnt & 3) * 16, y, 1.0f, lane);
      }
    }
  }

  // ---- GEMM2: [16,256] x [256,64] -> out (fp32, merged voxel layout) ----
  {
    f32x4 acc2[4];
    #pragma unroll
    for (int nt = 0; nt < 4; ++nt){
      float bb = b2[nt * 16 + c0];
      acc2[nt] = (f32x4){bb, bb, bb, bb};
    }
    #pragma unroll
    for (int kk = 0; kk < 8; ++kk){
      bf16x8 a = ldfrag<64>(sh + (kk >> 1) * 4096, tb, (kk & 1) * 32, lane);
      const u16* base = wf2 + kk * 4 * 512 + lane * 8;
      #pragma unroll
      for (int nt = 0; nt < 4; ++nt)
        acc2[nt] = __builtin_amdgcn_mfma_f32_16x16x32_bf16(
            a, *(const bf16x8*)(base + nt * 512), acc2[nt], 0, 0, 0);
    }
    #pragma unroll
    for (int r = 0; r < 4; ++r){
      int l = tb + g4 + r;
      int gd = d0 + (l >> 4), gh = h0 + ((l >> 2) & 3), gw = w0 + (l & 3);
      float* orow = out + ((gd * 64 + gh) * 64 + gw) * 64;
      #pragma unroll
      for (int nt = 0; nt < 4; ++nt)
        orow[nt * 16 + c0] = acc2[nt][r];
    }
  }
}

extern "C" void kernel_launch(void* const* d_in, const int* in_sizes, int n_in,
                              void* d_out, int out_size, void* d_ws, size_t ws_size,
                              hipStream_t stream){
  const float* x    = (const float*)d_in[0];
  const float* ln1g = (const float*)d_in[1];
  const float* ln1b = (const float*)d_in[2];
  const float* wq   = (const float*)d_in[3];
  const float* bq   = (const float*)d_in[4];
  const float* wk   = (const float*)d_in[5];
  const float* bk   = (const float*)d_in[6];
  const float* wv   = (const float*)d_in[7];
  const float* bv   = (const float*)d_in[8];
  const float* wo   = (const float*)d_in[9];
  const float* bo   = (const float*)d_in[10];
  const float* ln2g = (const float*)d_in[11];
  const float* ln2b = (const float*)d_in[12];
  const float* w1   = (const float*)d_in[13];
  const float* b1   = (const float*)d_in[14];
  const float* w2   = (const float*)d_in[15];
  const float* b2   = (const float*)d_in[16];

  u16* wf = (u16*)d_ws;     // 192KB bf16 weight fragments + 256B fp32 bias2
  float* out = (float*)d_out;

  k_prep<<<385, 256, 0, stream>>>(wq, wk, wv, wo, w1, w2, bv, bo, wf);
  k_mega<<<NWIN, 256, 0, stream>>>(x, ln1g, ln1b, bq, bk,
                                   ln2g, ln2b, b1, b2, wf, out);
}

// Round 19
// 134.834 us; speedup vs baseline: 1.9480x; 1.0437x over previous
//
#include <hip/hip_runtime.h>
#include <math.h>

#define NWIN 4096    // (64/4)^3 windows

typedef unsigned short u16;
typedef unsigned int u32;
typedef __bf16 bf16;
typedef __attribute__((ext_vector_type(8))) __bf16 bf16x8;
typedef __attribute__((ext_vector_type(4))) float f32x4;

__device__ __forceinline__ u16 f2b(float f){
  return __builtin_bit_cast(u16, (bf16)f);
}
__device__ __forceinline__ u32 pack2(float lo, float hi){
  return ((u32)f2b(hi) << 16) | (u32)f2b(lo);
}

// ---- DPP cross-lane (VALU-pipe) ----
// quad_perm xor1 = 0xB1; xor2 = 0x4E; row_ror:4 = 0x124, row_ror:8 = 0x128
template<int CTRL>
__device__ __forceinline__ float dppf(float v){
  return __builtin_bit_cast(float, __builtin_amdgcn_update_dpp(
      0, __builtin_bit_cast(int, v), CTRL, 0xF, 0xF, false));
}
__device__ __forceinline__ float grp16_sum(float v){
  v += dppf<0xB1>(v);
  v += dppf<0x4E>(v);
  v += dppf<0x124>(v);
  v += dppf<0x128>(v);
  return v;
}
__device__ __forceinline__ float grp16_max(float v){
  v = fmaxf(v, dppf<0xB1>(v));
  v = fmaxf(v, dppf<0x4E>(v));
  v = fmaxf(v, dppf<0x124>(v));
  v = fmaxf(v, dppf<0x128>(v));
  return v;
}
// GELU, sigmoid form: v*sigmoid(1.5957692*(v+0.044715 v^3)).
__device__ __forceinline__ float gelu(float v){
  float v2 = v * v;
  float inner = fmaf(v2, -0.07135806f, -1.5957692f);
  float e = __expf(v * inner);
  return v * __builtin_amdgcn_rcpf(1.0f + e);
}

// ---- LDS fragment helpers: bf16 tiles, XOR-swizzled (col ^ ((row&7)<<3)) ----
template<int STRIDE>
__device__ __forceinline__ bf16x8 ldfrag(const u16* m, int rowbase, int colbase, int lane){
  int row = rowbase + (lane & 15);
  int col = colbase + ((lane >> 4) << 3);
  return *(const bf16x8*)&m[row * STRIDE + (col ^ ((row & 7) << 3))];
}
template<int STRIDE>
__device__ __forceinline__ void stfrag(u16* m, int rowbase, int colbase, f32x4 v, int lane){
  int col = colbase + (lane & 15);
  int r0  = rowbase + ((lane >> 4) << 2);
  #pragma unroll
  for (int r = 0; r < 4; ++r){
    int row = r0 + r;
    m[row * STRIDE + (col ^ ((row & 7) << 3))] = f2b(v[r]);
  }
}
// store transposed: element (row,col) -> m[col][row]
__device__ __forceinline__ void stfragT(u16* m, int rowbase, int colbase, f32x4 v, int lane){
  int col = colbase + (lane & 15);
  int r0  = rowbase + ((lane >> 4) << 2);
  #pragma unroll
  for (int r = 0; r < 4; ++r){
    int row = r0 + r;
    m[col * 64 + (row ^ ((col & 7) << 3))] = f2b(v[r]);
  }
}

// ---------------- prep: weights -> bf16 B-fragment order in d_ws ----------------
// wfq: [mat3][head4][kk2][ct4][lane64][8]   49152 u16
//   mat0 = Wq * 0.125 (1/sqrt(KD) FOLDED), mat1 = Wk, mat2 = U_h = Wv_h @ Wo_h (FOLDED)
// (49152..65536 unused — old wfo slot, kept for layout stability)
// wf1: [kk2][nt16][lane64][8]               16384 u16 @ 65536
// wf2: [kk8][nt4][lane64][8]                16384 u16 @ 81920
// bias2: 64 fp32 @ u16-offset 98304         (bo + sum_h bv_h @ Wo_h)
__global__ __launch_bounds__(256) void k_prep(
    const float* __restrict__ wq, const float* __restrict__ wk,
    const float* __restrict__ wv, const float* __restrict__ wo,
    const float* __restrict__ w1, const float* __restrict__ w2,
    const float* __restrict__ bv, const float* __restrict__ bo,
    u16* __restrict__ wfq){
  int idx = blockIdx.x * 256 + threadIdx.x;
  if (idx >= 98368) return;
  int e = idx & 7, lane = (idx >> 3) & 63;
  if (idx < 49152){
    int ct = (idx >> 9) & 3, kk = (idx >> 11) & 1, hh = (idx >> 12) & 3, m = idx >> 14;
    int c = kk * 32 + ((lane >> 4) << 3) + e;
    int d = (ct << 4) + (lane & 15);
    if (m == 0){
      wfq[idx] = f2b(0.125f * wq[(c * 4 + hh) * 64 + d]);   // 1/sqrt(64) folded
    } else if (m == 1){
      wfq[idx] = f2b(wk[(c * 4 + hh) * 64 + d]);
    } else {
      // U_h[c][d] = sum_k Wv[(c,hh),k] * Wo[(hh,k),d]
      float s = 0.f;
      for (int k = 0; k < 64; ++k)
        s += wv[(c * 4 + hh) * 64 + k] * wo[(hh * 64 + k) * 64 + d];
      wfq[idx] = f2b(s);
    }
  } else if (idx < 65536){
    // old wfo slot: unused after the fold
  } else if (idx < 81920){
    int j = idx - 65536;
    int nt = (j >> 9) & 15, kk = (j >> 13) & 1;
    int c = kk * 32 + ((lane >> 4) << 3) + e;
    int f = nt * 16 + (lane & 15);
    wfq[idx] = f2b(w1[c * 256 + f]);
  } else if (idx < 98304){
    int j = idx - 81920;
    int nt = (j >> 9) & 3, kk = (j >> 11) & 7;
    int f = kk * 32 + ((lane >> 4) << 3) + e;
    int c = nt * 16 + (lane & 15);
    wfq[idx] = f2b(w2[f * 64 + c]);
  } else {
    int c = idx - 98304;          // 0..63
    float s = bo[c];
    for (int k = 0; k < 256; ++k) // hh*64+d
      s += bv[k] * wo[k * 64 + c];
    ((float*)(wfq + 98304))[c] = s;
  }
}

// ------- fused LN1 + window MHA (out-proj FOLDED into V) + x2 + LN2 + FFN -------
// ROUND 18 CHAMPION + algebraic folds: Q-scale folded into Wq/bq; x2 folded into
// LN2 eps (LN(2o) == (o-mu)/sqrt(var+2.5e-6)*g+b exactly); raw v_rcp/v_rsq for
// softmax denom and LN rsqrt. No structural/scheduling changes.
__global__ __launch_bounds__(256, 4) void k_mega(
    const float* __restrict__ x,
    const float* __restrict__ ln1g, const float* __restrict__ ln1b,
    const float* __restrict__ bq, const float* __restrict__ bk,
    const float* __restrict__ ln2g, const float* __restrict__ ln2b,
    const float* __restrict__ b1, const float* __restrict__ b2,
    const u16* __restrict__ wf,
    float* __restrict__ out){
  __shared__ alignas(16) u16 sh[16384];   // 32KB: 4 x [64][64] bf16 buffers
  u16* hs = sh;           // LN1(x); later LN2 result; later y1 col-block 0 (per-wave rows)
  u16* qs = sh + 4096;    // Q -> P (wave-private rows); later y1 cb1
  u16* ks = sh + 8192;    // K (cross-wave); later y1 cb2
  u16* vt = sh + 12288;   // V'^T (cross-wave); later y1 cb3
  const u16* wfq = wf;
  const u16* wf1 = wf + 65536;
  const u16* wf2 = wf + 81920;
  const float* bias2 = (const float*)(wf + 98304);

  int tid = threadIdx.x, wg = tid >> 6, lane = tid & 63;
  int win = blockIdx.x;
  int d0 = (win >> 8) << 2, h0 = ((win >> 4) & 15) << 2, w0 = (win & 15) << 2;
  int tb = wg * 16;
  int c0 = lane & 15, g4 = (lane >> 4) << 2;

  // ---- LN1, vectorized: lane holds 4 channels; each 16-lane DPP row = one token
  //      row; 4 rows per iteration. Own rows only: no barrier. ----
  {
    int c4 = c0 * 4;
    int sub = lane >> 4;
    const float4 g4v = *(const float4*)&ln1g[c4];
    const float4 b4v = *(const float4*)&ln1b[c4];
    #pragma unroll
    for (int i = 0; i < 4; ++i){
      int l = tb + i * 4 + sub;
      int gd = d0 + (l >> 4), gh = h0 + ((l >> 2) & 3), gw = w0 + (l & 3);
      const float4 xv = *(const float4*)&x[(((gd * 64 + gh) * 64 + gw) << 6) + c4];
      float s = grp16_sum(xv.x + xv.y + xv.z + xv.w);
      float mn = s * 0.015625f;
      float e0 = xv.x - mn, e1 = xv.y - mn, e2 = xv.z - mn, e3 = xv.w - mn;
      float q = grp16_sum(e0*e0 + e1*e1 + e2*e2 + e3*e3);
      float rs = __builtin_amdgcn_rsqf(q * 0.015625f + 1e-5f);
      float n0 = e0 * rs * g4v.x + b4v.x;
      float n1 = e1 * rs * g4v.y + b4v.y;
      float n2 = e2 * rs * g4v.z + b4v.z;
      float n3 = e3 * rs * g4v.w + b4v.w;
      // c4 is 4-aligned; XOR swizzle touches bits >=3 -> 8B-aligned uint2 store
      *(uint2*)&hs[l * 64 + (c4 ^ ((l & 7) << 3))] = (uint2){pack2(n0, n1), pack2(n2, n3)};
    }
  }

  f32x4 oacc[4];
  #pragma unroll
  for (int ct = 0; ct < 4; ++ct){
    float b0 = bias2[ct * 16 + c0];
    oacc[ct] = (f32x4){b0, b0, b0, b0};
  }

  for (int hh = 0; hh < 4; ++hh){
    // ---- Q/K/V' projection: three sequential passes (low reg pressure) ----
    #pragma unroll
    for (int m = 0; m < 3; ++m){
      f32x4 acc[4];
      #pragma unroll
      for (int ct = 0; ct < 4; ++ct){
        float bb = (m == 0) ? 0.125f * bq[hh * 64 + ct * 16 + c0]   // folded Q scale
                 : (m == 1) ? bk[hh * 64 + ct * 16 + c0] : 0.f;
        acc[ct] = (f32x4){bb, bb, bb, bb};
      }
      #pragma unroll
      for (int kk = 0; kk < 2; ++kk){
        bf16x8 a = ldfrag<64>(hs, tb, kk * 32, lane);
        const u16* base = wfq + m * 16384 + ((hh * 2 + kk) * 4) * 512 + lane * 8;
        #pragma unroll
        for (int ct = 0; ct < 4; ++ct)
          acc[ct] = __builtin_amdgcn_mfma_f32_16x16x32_bf16(
              a, *(const bf16x8*)(base + ct * 512), acc[ct], 0, 0, 0);
      }
      if (m == 0){
        #pragma unroll
        for (int ct = 0; ct < 4; ++ct) stfrag<64>(qs, tb, ct * 16, acc[ct], lane);
      } else if (m == 1){
        #pragma unroll
        for (int ct = 0; ct < 4; ++ct) stfrag<64>(ks, tb, ct * 16, acc[ct], lane);
      } else {
        #pragma unroll
        for (int ct = 0; ct < 4; ++ct) stfragT(vt, tb, ct * 16, acc[ct], lane);  // V'^T [c][m]
      }
    }
    __syncthreads();   // ks/vt read cross-wave

    // ---- att = Q K^T  (Q fully consumed from qs before P overwrites it) ----
    f32x4 att[4];
    #pragma unroll
    for (int ct = 0; ct < 4; ++ct) att[ct] = (f32x4){0.f, 0.f, 0.f, 0.f};
    #pragma unroll
    for (int kk = 0; kk < 2; ++kk){
      bf16x8 a = ldfrag<64>(qs, tb, kk * 32, lane);
      #pragma unroll
      for (int ct = 0; ct < 4; ++ct)
        att[ct] = __builtin_amdgcn_mfma_f32_16x16x32_bf16(
            a, ldfrag<64>(ks, ct * 16, kk * 32, lane), att[ct], 0, 0, 0);
    }

    // ---- in-register softmax over m (DPP 16-lane reductions; v_rcp denom) ----
    #pragma unroll
    for (int r = 0; r < 4; ++r){
      float m0 = fmaxf(fmaxf(att[0][r], att[1][r]), fmaxf(att[2][r], att[3][r]));
      m0 = grp16_max(m0);
      float e0 = __expf(att[0][r] - m0), e1 = __expf(att[1][r] - m0);
      float e2 = __expf(att[2][r] - m0), e3 = __expf(att[3][r] - m0);
      float s = grp16_sum(e0 + e1 + e2 + e3);
      float inv = __builtin_amdgcn_rcpf(s);
      att[0][r] = e0 * inv; att[1][r] = e1 * inv;
      att[2][r] = e2 * inv; att[3][r] = e3 * inv;
    }
    #pragma unroll
    for (int ct = 0; ct < 4; ++ct) stfrag<64>(qs, tb, ct * 16, att[ct], lane);  // P -> qs

    // ---- oacc += P V'  (out-proj folded into V'; fp32 accumulate, no LDS round-trip) ----
    #pragma unroll
    for (int kk = 0; kk < 2; ++kk){
      bf16x8 a = ldfrag<64>(qs, tb, kk * 32, lane);
      #pragma unroll
      for (int ct = 0; ct < 4; ++ct)
        oacc[ct] = __builtin_amdgcn_mfma_f32_16x16x32_bf16(
            a, ldfrag<64>(vt, ct * 16, kk * 32, lane), oacc[ct], 0, 0, 0);
    }
    __syncthreads();   // before next head overwrites ks/vt (and before FFN LDS reuse)
  }

  // ======== LN2 with x2 folded into eps (exact) + FFN (wave-private rows) ========
  {
    float g2[4], b2l[4];
    #pragma unroll
    for (int ct = 0; ct < 4; ++ct){
      g2[ct] = ln2g[ct * 16 + c0];
      b2l[ct] = ln2b[ct * 16 + c0];
    }
    #pragma unroll
    for (int r = 0; r < 4; ++r){
      float v0 = oacc[0][r], v1 = oacc[1][r];
      float v2 = oacc[2][r], v3 = oacc[3][r];
      float s = grp16_sum(v0 + v1 + v2 + v3);
      float mn = s * 0.015625f;
      float d0f = v0 - mn, d1 = v1 - mn, d2 = v2 - mn, d3 = v3 - mn;
      float q = grp16_sum(d0f*d0f + d1*d1 + d2*d2 + d3*d3);
      float rs = __builtin_amdgcn_rsqf(q * 0.015625f + 2.5e-6f);  // (eps/4): LN(2o)==this
      int row = tb + g4 + r;
      hs[row * 64 + ((0 * 16 + c0) ^ ((row & 7) << 3))] = f2b(d0f * rs * g2[0] + b2l[0]);
      hs[row * 64 + ((1 * 16 + c0) ^ ((row & 7) << 3))] = f2b(d1 * rs * g2[1] + b2l[1]);
      hs[row * 64 + ((2 * 16 + c0) ^ ((row & 7) << 3))] = f2b(d2 * rs * g2[2] + b2l[2]);
      hs[row * 64 + ((3 * 16 + c0) ^ ((row & 7) << 3))] = f2b(d3 * rs * g2[3] + b2l[3]);
    }
  }

  // ---- GEMM1: [16,64] x [64,256] -> y1 (GELU, bf16) ----
  // y1 col-block cb (64 cols) lives in buffer cb at this wave's own rows tb..tb+15.
  // Preload both hs A-fragments BEFORE y1 overwrites the hs slice.
  {
    bf16x8 a0 = ldfrag<64>(hs, tb, 0, lane);
    bf16x8 a1 = ldfrag<64>(hs, tb, 32, lane);
    #pragma unroll
    for (int half = 0; half < 2; ++half){
      f32x4 acc1[8];
      #pragma unroll
      for (int nt = 0; nt < 8; ++nt){
        float bb = b1[(half * 8 + nt) * 16 + c0];
        acc1[nt] = (f32x4){bb, bb, bb, bb};
      }
      const u16* base0 = wf1 + half * 8 * 512 + lane * 8;
      #pragma unroll
      for (int nt = 0; nt < 8; ++nt)
        acc1[nt] = __builtin_amdgcn_mfma_f32_16x16x32_bf16(
            a0, *(const bf16x8*)(base0 + nt * 512), acc1[nt], 0, 0, 0);
      #pragma unroll
      for (int nt = 0; nt < 8; ++nt)
        acc1[nt] = __builtin_amdgcn_mfma_f32_16x16x32_bf16(
            a1, *(const bf16x8*)(base0 + 16 * 512 + nt * 512), acc1[nt], 0, 0, 0);
      #pragma unroll
      for (int nt = 0; nt < 8; ++nt){
        f32x4 v = acc1[nt];
        f32x4 y;
        #pragma unroll
        for (int r = 0; r < 4; ++r) y[r] = gelu(v[r]);
        int gnt = half * 8 + nt;                 // global col tile 0..15
        stfrag<64>(sh + (gnt >> 2) * 4096, tb, (gnt & 3) * 16, y, lane);
      }
    }
  }

  // ---- GEMM2: [16,256] x [256,64] -> out (fp32, merged voxel layout) ----
  {
    f32x4 acc2[4];
    #pragma unroll
    for (int nt = 0; nt < 4; ++nt){
      float bb = b2[nt * 16 + c0];
      acc2[nt] = (f32x4){bb, bb, bb, bb};
    }
    #pragma unroll
    for (int kk = 0; kk < 8; ++kk){
      bf16x8 a = ldfrag<64>(sh + (kk >> 1) * 4096, tb, (kk & 1) * 32, lane);
      const u16* base = wf2 + kk * 4 * 512 + lane * 8;
      #pragma unroll
      for (int nt = 0; nt < 4; ++nt)
        acc2[nt] = __builtin_amdgcn_mfma_f32_16x16x32_bf16(
            a, *(const bf16x8*)(base + nt * 512), acc2[nt], 0, 0, 0);
    }
    #pragma unroll
    for (int r = 0; r < 4; ++r){
      int l = tb + g4 + r;
      int gd = d0 + (l >> 4), gh = h0 + ((l >> 2) & 3), gw = w0 + (l & 3);
      float* orow = out + ((gd * 64 + gh) * 64 + gw) * 64;
      #pragma unroll
      for (int nt = 0; nt < 4; ++nt)
        orow[nt * 16 + c0] = acc2[nt][r];
    }
  }
}

extern "C" void kernel_launch(void* const* d_in, const int* in_sizes, int n_in,
                              void* d_out, int out_size, void* d_ws, size_t ws_size,
                              hipStream_t stream){
  const float* x    = (const float*)d_in[0];
  const float* ln1g = (const float*)d_in[1];
  const float* ln1b = (const float*)d_in[2];
  const float* wq   = (const float*)d_in[3];
  const float* bq   = (const float*)d_in[4];
  const float* wk   = (const float*)d_in[5];
  const float* bk   = (const float*)d_in[6];
  const float* wv   = (const float*)d_in[7];
  const float* bv   = (const float*)d_in[8];
  const float* wo   = (const float*)d_in[9];
  const float* bo   = (const float*)d_in[10];
  const float* ln2g = (const float*)d_in[11];
  const float* ln2b = (const float*)d_in[12];
  const float* w1   = (const float*)d_in[13];
  const float* b1   = (const float*)d_in[14];
  const float* w2   = (const float*)d_in[15];
  const float* b2   = (const float*)d_in[16];

  u16* wf = (u16*)d_ws;     // 192KB bf16 weight fragments + 256B fp32 bias2
  float* out = (float*)d_out;

  k_prep<<<385, 256, 0, stream>>>(wq, wk, wv, wo, w1, w2, bv, bo, wf);
  k_mega<<<NWIN, 256, 0, stream>>>(x, ln1g, ln1b, bq, bk,
                                   ln2g, ln2b, b1, b2, wf, out);
}

// Round 20
// 133.137 us; speedup vs baseline: 1.9728x; 1.0128x over previous
//
#include <hip/hip_runtime.h>
#include <math.h>

#define NWIN 4096    // (64/4)^3 windows

typedef unsigned short u16;
typedef unsigned int u32;
typedef __bf16 bf16;
typedef __attribute__((ext_vector_type(8))) __bf16 bf16x8;
typedef __attribute__((ext_vector_type(4))) float f32x4;

__device__ __forceinline__ u16 f2b(float f){
  return __builtin_bit_cast(u16, (bf16)f);
}
__device__ __forceinline__ u32 pack2(float lo, float hi){
  return ((u32)f2b(hi) << 16) | (u32)f2b(lo);
}

// ---- DPP cross-lane (VALU-pipe) ----
// quad_perm xor1 = 0xB1; xor2 = 0x4E; row_ror:4 = 0x124, row_ror:8 = 0x128
template<int CTRL>
__device__ __forceinline__ float dppf(float v){
  return __builtin_bit_cast(float, __builtin_amdgcn_update_dpp(
      0, __builtin_bit_cast(int, v), CTRL, 0xF, 0xF, false));
}
__device__ __forceinline__ float grp16_sum(float v){
  v += dppf<0xB1>(v);
  v += dppf<0x4E>(v);
  v += dppf<0x124>(v);
  v += dppf<0x128>(v);
  return v;
}
__device__ __forceinline__ float grp16_max(float v){
  v = fmaxf(v, dppf<0xB1>(v));
  v = fmaxf(v, dppf<0x4E>(v));
  v = fmaxf(v, dppf<0x124>(v));
  v = fmaxf(v, dppf<0x128>(v));
  return v;
}
// GELU, sigmoid form in exp2 domain: v*sigmoid(1.5957692*(v+0.044715 v^3)),
// constants pre-multiplied by log2(e) so v_exp_f32 (2^x) is used directly.
__device__ __forceinline__ float gelu(float v){
  float v2 = v * v;
  float inner = fmaf(v2, -0.1029484f, -2.3022090f);   // log2e-folded
  float e = __builtin_amdgcn_exp2f(v * inner);
  return v * __builtin_amdgcn_rcpf(1.0f + e);
}

// ---- LDS fragment helpers: bf16 tiles, XOR-swizzled (col ^ ((row&7)<<3)) ----
template<int STRIDE>
__device__ __forceinline__ bf16x8 ldfrag(const u16* m, int rowbase, int colbase, int lane){
  int row = rowbase + (lane & 15);
  int col = colbase + ((lane >> 4) << 3);
  return *(const bf16x8*)&m[row * STRIDE + (col ^ ((row & 7) << 3))];
}
template<int STRIDE>
__device__ __forceinline__ void stfrag(u16* m, int rowbase, int colbase, f32x4 v, int lane){
  int col = colbase + (lane & 15);
  int r0  = rowbase + ((lane >> 4) << 2);
  #pragma unroll
  for (int r = 0; r < 4; ++r){
    int row = r0 + r;
    m[row * STRIDE + (col ^ ((row & 7) << 3))] = f2b(v[r]);
  }
}
// store transposed: element (row,col) -> m[col][row]
__device__ __forceinline__ void stfragT(u16* m, int rowbase, int colbase, f32x4 v, int lane){
  int col = colbase + (lane & 15);
  int r0  = rowbase + ((lane >> 4) << 2);
  #pragma unroll
  for (int r = 0; r < 4; ++r){
    int row = r0 + r;
    m[col * 64 + (row ^ ((col & 7) << 3))] = f2b(v[r]);
  }
}

// ---------------- prep: weights -> bf16 B-fragment order in d_ws ----------------
// wfq: [mat3][head4][kk2][ct4][lane64][8]   49152 u16
//   mat0 = Wq * 0.125*log2e (Q-scale AND exp->exp2 conversion FOLDED)
//   mat1 = Wk, mat2 = U_h = Wv_h @ Wo_h (out-proj FOLDED)
// (49152..65536 unused — old wfo slot, kept for layout stability)
// wf1: [kk2][nt16][lane64][8]               16384 u16 @ 65536
// wf2: [kk8][nt4][lane64][8]                16384 u16 @ 81920
// bias2: 64 fp32 @ u16-offset 98304         (bo + sum_h bv_h @ Wo_h)
__global__ __launch_bounds__(256) void k_prep(
    const float* __restrict__ wq, const float* __restrict__ wk,
    const float* __restrict__ wv, const float* __restrict__ wo,
    const float* __restrict__ w1, const float* __restrict__ w2,
    const float* __restrict__ bv, const float* __restrict__ bo,
    u16* __restrict__ wfq){
  int idx = blockIdx.x * 256 + threadIdx.x;
  if (idx >= 98368) return;
  int e = idx & 7, lane = (idx >> 3) & 63;
  if (idx < 49152){
    int ct = (idx >> 9) & 3, kk = (idx >> 11) & 1, hh = (idx >> 12) & 3, m = idx >> 14;
    int c = kk * 32 + ((lane >> 4) << 3) + e;
    int d = (ct << 4) + (lane & 15);
    if (m == 0){
      wfq[idx] = f2b(0.18033688f * wq[(c * 4 + hh) * 64 + d]);  // 0.125*log2e folded
    } else if (m == 1){
      wfq[idx] = f2b(wk[(c * 4 + hh) * 64 + d]);
    } else {
      // U_h[c][d] = sum_k Wv[(c,hh),k] * Wo[(hh,k),d]
      float s = 0.f;
      for (int k = 0; k < 64; ++k)
        s += wv[(c * 4 + hh) * 64 + k] * wo[(hh * 64 + k) * 64 + d];
      wfq[idx] = f2b(s);
    }
  } else if (idx < 65536){
    // old wfo slot: unused after the fold
  } else if (idx < 81920){
    int j = idx - 65536;
    int nt = (j >> 9) & 15, kk = (j >> 13) & 1;
    int c = kk * 32 + ((lane >> 4) << 3) + e;
    int f = nt * 16 + (lane & 15);
    wfq[idx] = f2b(w1[c * 256 + f]);
  } else if (idx < 98304){
    int j = idx - 81920;
    int nt = (j >> 9) & 3, kk = (j >> 11) & 7;
    int f = kk * 32 + ((lane >> 4) << 3) + e;
    int c = nt * 16 + (lane & 15);
    wfq[idx] = f2b(w2[f * 64 + c]);
  } else {
    int c = idx - 98304;          // 0..63
    float s = bo[c];
    for (int k = 0; k < 256; ++k) // hh*64+d
      s += bv[k] * wo[k * 64 + c];
    ((float*)(wfq + 98304))[c] = s;
  }
}

// ------- fused LN1 + window MHA (out-proj FOLDED into V) + x2 + LN2 + FFN -------
// ROUND 19 CHAMPION + exp2-domain softmax (log2e folded into Wq/bq; v_exp_f32
// direct) + exp2-domain GELU. softmax(att'*log2e base-2) == softmax(att base-e)
// exactly (max commutes with positive scale). No structural changes.
__global__ __launch_bounds__(256, 4) void k_mega(
    const float* __restrict__ x,
    const float* __restrict__ ln1g, const float* __restrict__ ln1b,
    const float* __restrict__ bq, const float* __restrict__ bk,
    const float* __restrict__ ln2g, const float* __restrict__ ln2b,
    const float* __restrict__ b1, const float* __restrict__ b2,
    const u16* __restrict__ wf,
    float* __restrict__ out){
  __shared__ alignas(16) u16 sh[16384];   // 32KB: 4 x [64][64] bf16 buffers
  u16* hs = sh;           // LN1(x); later LN2 result; later y1 col-block 0 (per-wave rows)
  u16* qs = sh + 4096;    // Q -> P (wave-private rows); later y1 cb1
  u16* ks = sh + 8192;    // K (cross-wave); later y1 cb2
  u16* vt = sh + 12288;   // V'^T (cross-wave); later y1 cb3
  const u16* wfq = wf;
  const u16* wf1 = wf + 65536;
  const u16* wf2 = wf + 81920;
  const float* bias2 = (const float*)(wf + 98304);

  int tid = threadIdx.x, wg = tid >> 6, lane = tid & 63;
  int win = blockIdx.x;
  int d0 = (win >> 8) << 2, h0 = ((win >> 4) & 15) << 2, w0 = (win & 15) << 2;
  int tb = wg * 16;
  int c0 = lane & 15, g4 = (lane >> 4) << 2;

  // ---- LN1, vectorized: lane holds 4 channels; each 16-lane DPP row = one token
  //      row; 4 rows per iteration. Own rows only: no barrier. ----
  {
    int c4 = c0 * 4;
    int sub = lane >> 4;
    const float4 g4v = *(const float4*)&ln1g[c4];
    const float4 b4v = *(const float4*)&ln1b[c4];
    #pragma unroll
    for (int i = 0; i < 4; ++i){
      int l = tb + i * 4 + sub;
      int gd = d0 + (l >> 4), gh = h0 + ((l >> 2) & 3), gw = w0 + (l & 3);
      const float4 xv = *(const float4*)&x[(((gd * 64 + gh) * 64 + gw) << 6) + c4];
      float s = grp16_sum(xv.x + xv.y + xv.z + xv.w);
      float mn = s * 0.015625f;
      float e0 = xv.x - mn, e1 = xv.y - mn, e2 = xv.z - mn, e3 = xv.w - mn;
      float q = grp16_sum(e0*e0 + e1*e1 + e2*e2 + e3*e3);
      float rs = __builtin_amdgcn_rsqf(q * 0.015625f + 1e-5f);
      float n0 = e0 * rs * g4v.x + b4v.x;
      float n1 = e1 * rs * g4v.y + b4v.y;
      float n2 = e2 * rs * g4v.z + b4v.z;
      float n3 = e3 * rs * g4v.w + b4v.w;
      // c4 is 4-aligned; XOR swizzle touches bits >=3 -> 8B-aligned uint2 store
      *(uint2*)&hs[l * 64 + (c4 ^ ((l & 7) << 3))] = (uint2){pack2(n0, n1), pack2(n2, n3)};
    }
  }

  f32x4 oacc[4];
  #pragma unroll
  for (int ct = 0; ct < 4; ++ct){
    float b0 = bias2[ct * 16 + c0];
    oacc[ct] = (f32x4){b0, b0, b0, b0};
  }

  for (int hh = 0; hh < 4; ++hh){
    // ---- Q/K/V' projection: three sequential passes (low reg pressure) ----
    #pragma unroll
    for (int m = 0; m < 3; ++m){
      f32x4 acc[4];
      #pragma unroll
      for (int ct = 0; ct < 4; ++ct){
        float bb = (m == 0) ? 0.18033688f * bq[hh * 64 + ct * 16 + c0]  // folded scale
                 : (m == 1) ? bk[hh * 64 + ct * 16 + c0] : 0.f;
        acc[ct] = (f32x4){bb, bb, bb, bb};
      }
      #pragma unroll
      for (int kk = 0; kk < 2; ++kk){
        bf16x8 a = ldfrag<64>(hs, tb, kk * 32, lane);
        const u16* base = wfq + m * 16384 + ((hh * 2 + kk) * 4) * 512 + lane * 8;
        #pragma unroll
        for (int ct = 0; ct < 4; ++ct)
          acc[ct] = __builtin_amdgcn_mfma_f32_16x16x32_bf16(
              a, *(const bf16x8*)(base + ct * 512), acc[ct], 0, 0, 0);
      }
      if (m == 0){
        #pragma unroll
        for (int ct = 0; ct < 4; ++ct) stfrag<64>(qs, tb, ct * 16, acc[ct], lane);
      } else if (m == 1){
        #pragma unroll
        for (int ct = 0; ct < 4; ++ct) stfrag<64>(ks, tb, ct * 16, acc[ct], lane);
      } else {
        #pragma unroll
        for (int ct = 0; ct < 4; ++ct) stfragT(vt, tb, ct * 16, acc[ct], lane);  // V'^T [c][m]
      }
    }
    __syncthreads();   // ks/vt read cross-wave

    // ---- att = Q K^T  (log2e-scaled domain; Q fully consumed before P overwrites) ----
    f32x4 att[4];
    #pragma unroll
    for (int ct = 0; ct < 4; ++ct) att[ct] = (f32x4){0.f, 0.f, 0.f, 0.f};
    #pragma unroll
    for (int kk = 0; kk < 2; ++kk){
      bf16x8 a = ldfrag<64>(qs, tb, kk * 32, lane);
      #pragma unroll
      for (int ct = 0; ct < 4; ++ct)
        att[ct] = __builtin_amdgcn_mfma_f32_16x16x32_bf16(
            a, ldfrag<64>(ks, ct * 16, kk * 32, lane), att[ct], 0, 0, 0);
    }

    // ---- in-register softmax over m (DPP reductions; raw v_exp_f32 = 2^x) ----
    #pragma unroll
    for (int r = 0; r < 4; ++r){
      float m0 = fmaxf(fmaxf(att[0][r], att[1][r]), fmaxf(att[2][r], att[3][r]));
      m0 = grp16_max(m0);
      float e0 = __builtin_amdgcn_exp2f(att[0][r] - m0);
      float e1 = __builtin_amdgcn_exp2f(att[1][r] - m0);
      float e2 = __builtin_amdgcn_exp2f(att[2][r] - m0);
      float e3 = __builtin_amdgcn_exp2f(att[3][r] - m0);
      float s = grp16_sum(e0 + e1 + e2 + e3);
      float inv = __builtin_amdgcn_rcpf(s);
      att[0][r] = e0 * inv; att[1][r] = e1 * inv;
      att[2][r] = e2 * inv; att[3][r] = e3 * inv;
    }
    #pragma unroll
    for (int ct = 0; ct < 4; ++ct) stfrag<64>(qs, tb, ct * 16, att[ct], lane);  // P -> qs

    // ---- oacc += P V'  (out-proj folded into V'; fp32 accumulate, no LDS round-trip) ----
    #pragma unroll
    for (int kk = 0; kk < 2; ++kk){
      bf16x8 a = ldfrag<64>(qs, tb, kk * 32, lane);
      #pragma unroll
      for (int ct = 0; ct < 4; ++ct)
        oacc[ct] = __builtin_amdgcn_mfma_f32_16x16x32_bf16(
            a, ldfrag<64>(vt, ct * 16, kk * 32, lane), oacc[ct], 0, 0, 0);
    }
    __syncthreads();   // before next head overwrites ks/vt (and before FFN LDS reuse)
  }

  // ======== LN2 with x2 folded into eps (exact) + FFN (wave-private rows) ========
  {
    float g2[4], b2l[4];
    #pragma unroll
    for (int ct = 0; ct < 4; ++ct){
      g2[ct] = ln2g[ct * 16 + c0];
      b2l[ct] = ln2b[ct * 16 + c0];
    }
    #pragma unroll
    for (int r = 0; r < 4; ++r){
      float v0 = oacc[0][r], v1 = oacc[1][r];
      float v2 = oacc[2][r], v3 = oacc[3][r];
      float s = grp16_sum(v0 + v1 + v2 + v3);
      float mn = s * 0.015625f;
      float d0f = v0 - mn, d1 = v1 - mn, d2 = v2 - mn, d3 = v3 - mn;
      float q = grp16_sum(d0f*d0f + d1*d1 + d2*d2 + d3*d3);
      float rs = __builtin_amdgcn_rsqf(q * 0.015625f + 2.5e-6f);  // (eps/4): LN(2o)==this
      int row = tb + g4 + r;
      hs[row * 64 + ((0 * 16 + c0) ^ ((row & 7) << 3))] = f2b(d0f * rs * g2[0] + b2l[0]);
      hs[row * 64 + ((1 * 16 + c0) ^ ((row & 7) << 3))] = f2b(d1 * rs * g2[1] + b2l[1]);
      hs[row * 64 + ((2 * 16 + c0) ^ ((row & 7) << 3))] = f2b(d2 * rs * g2[2] + b2l[2]);
      hs[row * 64 + ((3 * 16 + c0) ^ ((row & 7) << 3))] = f2b(d3 * rs * g2[3] + b2l[3]);
    }
  }

  // ---- GEMM1: [16,64] x [64,256] -> y1 (GELU, bf16) ----
  // y1 col-block cb (64 cols) lives in buffer cb at this wave's own rows tb..tb+15.
  // Preload both hs A-fragments BEFORE y1 overwrites the hs slice.
  {
    bf16x8 a0 = ldfrag<64>(hs, tb, 0, lane);
    bf16x8 a1 = ldfrag<64>(hs, tb, 32, lane);
    #pragma unroll
    for (int half = 0; half < 2; ++half){
      f32x4 acc1[8];
      #pragma unroll
      for (int nt = 0; nt < 8; ++nt){
        float bb = b1[(half * 8 + nt) * 16 + c0];
        acc1[nt] = (f32x4){bb, bb, bb, bb};
      }
      const u16* base0 = wf1 + half * 8 * 512 + lane * 8;
      #pragma unroll
      for (int nt = 0; nt < 8; ++nt)
        acc1[nt] = __builtin_amdgcn_mfma_f32_16x16x32_bf16(
            a0, *(const bf16x8*)(base0 + nt * 512), acc1[nt], 0, 0, 0);
      #pragma unroll
      for (int nt = 0; nt < 8; ++nt)
        acc1[nt] = __builtin_amdgcn_mfma_f32_16x16x32_bf16(
            a1, *(const bf16x8*)(base0 + 16 * 512 + nt * 512), acc1[nt], 0, 0, 0);
      #pragma unroll
      for (int nt = 0; nt < 8; ++nt){
        f32x4 v = acc1[nt];
        f32x4 y;
        #pragma unroll
        for (int r = 0; r < 4; ++r) y[r] = gelu(v[r]);
        int gnt = half * 8 + nt;                 // global col tile 0..15
        stfrag<64>(sh + (gnt >> 2) * 4096, tb, (gnt & 3) * 16, y, lane);
      }
    }
  }

  // ---- GEMM2: [16,256] x [256,64] -> out (fp32, merged voxel layout) ----
  {
    f32x4 acc2[4];
    #pragma unroll
    for (int nt = 0; nt < 4; ++nt){
      float bb = b2[nt * 16 + c0];
      acc2[nt] = (f32x4){bb, bb, bb, bb};
    }
    #pragma unroll
    for (int kk = 0; kk < 8; ++kk){
      bf16x8 a = ldfrag<64>(sh + (kk >> 1) * 4096, tb, (kk & 1) * 32, lane);
      const u16* base = wf2 + kk * 4 * 512 + lane * 8;
      #pragma unroll
      for (int nt = 0; nt < 4; ++nt)
        acc2[nt] = __builtin_amdgcn_mfma_f32_16x16x32_bf16(
            a, *(const bf16x8*)(base + nt * 512), acc2[nt], 0, 0, 0);
    }
    #pragma unroll
    for (int r = 0; r < 4; ++r){
      int l = tb + g4 + r;
      int gd = d0 + (l >> 4), gh = h0 + ((l >> 2) & 3), gw = w0 + (l & 3);
      float* orow = out + ((gd * 64 + gh) * 64 + gw) * 64;
      #pragma unroll
      for (int nt = 0; nt < 4; ++nt)
        orow[nt * 16 + c0] = acc2[nt][r];
    }
  }
}

extern "C" void kernel_launch(void* const* d_in, const int* in_sizes, int n_in,
                              void* d_out, int out_size, void* d_ws, size_t ws_size,
                              hipStream_t stream){
  const float* x    = (const float*)d_in[0];
  const float* ln1g = (const float*)d_in[1];
  const float* ln1b = (const float*)d_in[2];
  const float* wq   = (const float*)d_in[3];
  const float* bq   = (const float*)d_in[4];
  const float* wk   = (const float*)d_in[5];
  const float* bk   = (const float*)d_in[6];
  const float* wv   = (const float*)d_in[7];
  const float* bv   = (const float*)d_in[8];
  const float* wo   = (const float*)d_in[9];
  const float* bo   = (const float*)d_in[10];
  const float* ln2g = (const float*)d_in[11];
  const float* ln2b = (const float*)d_in[12];
  const float* w1   = (const float*)d_in[13];
  const float* b1   = (const float*)d_in[14];
  const float* w2   = (const float*)d_in[15];
  const float* b2   = (const float*)d_in[16];

  u16* wf = (u16*)d_ws;     // 192KB bf16 weight fragments + 256B fp32 bias2
  float* out = (float*)d_out;

  k_prep<<<385, 256, 0, stream>>>(wq, wk, wv, wo, w1, w2, bv, bo, wf);
  k_mega<<<NWIN, 256, 0, stream>>>(x, ln1g, ln1b, bq, bk,
                                   ln2g, ln2b, b1, b2, wf, out);
}